// Round 1
// baseline (2873.730 us; speedup 1.0000x reference)
//
#include <hip/hip_runtime.h>
#include <hip/hip_bf16.h>
#include <math.h>

#define BATCH 8
#define NPTS  2048
#define KNN   20
#define NEG_INF (-3.402823466e38f)

static __device__ __forceinline__ float bn_scale(float g){ return g * rsqrtf(1.0f + 1e-5f); }

// ---------------- squared norms per point ----------------
__global__ void sqnorm_kernel(const float* __restrict__ X, float* __restrict__ sq, int C){
  int i = blockIdx.x*blockDim.x + threadIdx.x;
  if (i >= BATCH*NPTS) return;
  int b = i / NPTS, n = i - b*NPTS;
  const float* xb = X + (size_t)b*C*NPTS + n;
  float s = 0.f;
  for (int c=0;c<C;++c){ float v = xb[(size_t)c*NPTS]; s += v*v; }
  sq[i] = s;
}

// ---------------- kNN: one block per (b,n), top-20 by iterative argmax ----------------
template<int C>
__global__ __launch_bounds__(256) void knn_kernel(const float* __restrict__ X,
                                                  const float* __restrict__ sq,
                                                  int* __restrict__ idxout){
  const int n = blockIdx.x, b = blockIdx.y, t = threadIdx.x;
  __shared__ float ctr[C];
  __shared__ __align__(16) float dist[NPTS];
  __shared__ float redv[256];
  __shared__ int   redi[256];
  const float* xb = X + (size_t)b*C*NPTS;
  if (t < C) ctr[t] = xb[(size_t)t*NPTS + n];
  __syncthreads();
  const float sqn = sq[b*NPTS + n];
  for (int base=0; base<NPTS; base+=1024){
    int m0 = base + 4*t;
    float dx=0.f, dy=0.f, dz=0.f, dw=0.f;
    for (int c=0;c<C;++c){
      const float cv = ctr[c];
      const float4 xm = *(const float4*)&xb[(size_t)c*NPTS + m0];
      dx += cv*xm.x; dy += cv*xm.y; dz += cv*xm.z; dw += cv*xm.w;
    }
    const float4 s4 = *(const float4*)&sq[b*NPTS + m0];
    float4 dd;
    dd.x = 2.f*dx - sqn - s4.x;
    dd.y = 2.f*dy - sqn - s4.y;
    dd.z = 2.f*dz - sqn - s4.z;
    dd.w = 2.f*dw - sqn - s4.w;
    *(float4*)&dist[m0] = dd;
  }
  __syncthreads();
  int* row = idxout + ((size_t)b*NPTS + n)*KNN;
  for (int j=0;j<KNN;++j){
    float bv = NEG_INF; int bi = NPTS;
    for (int m=t; m<NPTS; m+=256){
      float v = dist[m];
      if (v > bv){ bv = v; bi = m; }   // ascending m => first max kept (smallest index)
    }
    redv[t]=bv; redi[t]=bi;
    __syncthreads();
    for (int s=128; s>0; s>>=1){
      if (t < s){
        float ov = redv[t+s]; int oi = redi[t+s];
        if (ov > redv[t] || (ov == redv[t] && oi < redi[t])){ redv[t]=ov; redi[t]=oi; }
      }
      __syncthreads();
    }
    if (t == 0){ row[j] = redi[0]; dist[redi[0]] = NEG_INF; }
    __syncthreads();
  }
}

// ---------------- weight prep: wnT[c][o] = w[o][c]; wdT[c][o] = w[o][C+c]-w[o][c] ----------------
__global__ void wprep_kernel(const float* __restrict__ w, float* __restrict__ wnT,
                             float* __restrict__ wdT, int O, int C){
  int i = blockIdx.x*blockDim.x + threadIdx.x;
  if (i >= O*C) return;
  int c = i / O, o = i - c*O;
  float a = w[(size_t)o*2*C + c];
  wnT[(size_t)c*O + o] = a;
  wdT[(size_t)c*O + o] = w[(size_t)o*2*C + C + c] - a;
}

__global__ void transpose_kernel(const float* __restrict__ w, float* __restrict__ wT, int O, int C){
  int i = blockIdx.x*blockDim.x + threadIdx.x;
  if (i >= O*C) return;
  int c = i / O, o = i - c*O;
  wT[(size_t)c*O + o] = w[(size_t)o*C + c];
}

// ---------------- edge conv: block per (b,n), thread = output channel o ----------------
template<int C, int O>
__global__ __launch_bounds__(O) void edgeconv_kernel(const float* __restrict__ X,
    const int* __restrict__ idx, const float* __restrict__ wnT, const float* __restrict__ wdT,
    const float* __restrict__ g, const float* __restrict__ bb, float* __restrict__ out){
  const int n = blockIdx.x, b = blockIdx.y, t = threadIdx.x;
  __shared__ __align__(16) float ctr[(C+3)&~3];
  __shared__ __align__(16) float nbr[KNN][C];
  const float* xb = X + (size_t)b*C*NPTS;
  const int* row = idx + ((size_t)b*NPTS + n)*KNN;
  for (int c=t; c<C; c+=O) ctr[c] = xb[(size_t)c*NPTS + n];
  for (int i=t; i<KNN*C; i+=O){
    int k = i / C, c = i - k*C;
    nbr[k][c] = xb[(size_t)c*NPTS + row[k]];
  }
  __syncthreads();
  float acc[KNN];
  #pragma unroll
  for (int k=0;k<KNN;++k) acc[k] = 0.f;
  float cst = 0.f;
  if constexpr ((C & 3) == 0){
    for (int c=0;c<C;c+=4){
      const float w0 = wnT[(c+0)*O+t], w1 = wnT[(c+1)*O+t], w2 = wnT[(c+2)*O+t], w3 = wnT[(c+3)*O+t];
      const float4 ct = *(const float4*)&ctr[c];
      cst += ct.x*wdT[(c+0)*O+t] + ct.y*wdT[(c+1)*O+t] + ct.z*wdT[(c+2)*O+t] + ct.w*wdT[(c+3)*O+t];
      #pragma unroll
      for (int k=0;k<KNN;++k){
        const float4 nb = *(const float4*)&nbr[k][c];
        acc[k] += nb.x*w0 + nb.y*w1 + nb.z*w2 + nb.w*w3;
      }
    }
  } else {
    for (int c=0;c<C;++c){
      const float wn = wnT[c*O+t];
      cst += ctr[c]*wdT[c*O+t];
      #pragma unroll
      for (int k=0;k<KNN;++k) acc[k] += nbr[k][c]*wn;
    }
  }
  float best = NEG_INF;
  #pragma unroll
  for (int k=0;k<KNN;++k) best = fmaxf(best, acc[k]);
  float v = (best + cst) * bn_scale(g[t]) + bb[t];
  out[((size_t)b*O + t)*NPTS + n] = fmaxf(v, 0.f);
}

// ---------------- conv5 GEMM (512 -> 1024 per point) + bn/relu + max over n ----------------
__global__ __launch_bounds__(256) void conv5_kernel(const float* __restrict__ x1,
  const float* __restrict__ x2, const float* __restrict__ x3, const float* __restrict__ x4,
  const float* __restrict__ w5T, const float* __restrict__ g, const float* __restrict__ bb,
  float* __restrict__ out5){
  const int b = blockIdx.z;
  const int otile = blockIdx.y*64, ntile = blockIdx.x*64;
  const int t = threadIdx.x, tx = t & 15, ty = t >> 4;
  __shared__ __align__(16) float Xs[16][68];
  __shared__ __align__(16) float Ws[16][64];
  __shared__ float red[64][17];
  float acc[4][4] = {{0.f}};
  for (int c0=0;c0<512;c0+=16){
    const float* src; int coff;
    if (c0 < 64)      { src = x1 + (size_t)b*64*NPTS;  coff = c0; }
    else if (c0 <128) { src = x2 + (size_t)b*64*NPTS;  coff = c0-64; }
    else if (c0 <256) { src = x3 + (size_t)b*128*NPTS; coff = c0-128; }
    else              { src = x4 + (size_t)b*256*NPTS; coff = c0-256; }
    *(float4*)&Xs[ty][tx*4] = *(const float4*)&src[(size_t)(coff+ty)*NPTS + ntile + tx*4];
    *(float4*)&Ws[ty][tx*4] = *(const float4*)&w5T[(size_t)(c0+ty)*1024 + otile + tx*4];
    __syncthreads();
    #pragma unroll
    for (int i=0;i<16;++i){
      const float4 wv = *(const float4*)&Ws[i][ty*4];
      const float4 xv = *(const float4*)&Xs[i][tx*4];
      const float wa[4] = {wv.x,wv.y,wv.z,wv.w};
      const float xa[4] = {xv.x,xv.y,xv.z,xv.w};
      #pragma unroll
      for (int io=0;io<4;++io)
        #pragma unroll
        for (int in_=0;in_<4;++in_) acc[io][in_] += wa[io]*xa[in_];
    }
    __syncthreads();
  }
  #pragma unroll
  for (int io=0;io<4;++io){
    const int o = otile + ty*4 + io;
    const float gg = bn_scale(g[o]), bv = bb[o];
    float mx = NEG_INF;
    #pragma unroll
    for (int in_=0;in_<4;++in_) mx = fmaxf(mx, fmaxf(acc[io][in_]*gg + bv, 0.f));
    red[ty*4+io][tx] = mx;
  }
  __syncthreads();
  if (t < 64){
    float mx = red[t][0];
    #pragma unroll
    for (int j=1;j<16;++j) mx = fmaxf(mx, red[t][j]);
    atomicMax((int*)&out5[(size_t)b*1024 + otile + t], __float_as_int(mx));
  }
}

__global__ void zero_kernel(float* __restrict__ p, int nfloats){
  int i = blockIdx.x*blockDim.x + threadIdx.x;
  if (i < nfloats) p[i] = 0.f;
}

// ---------------- FC layers ----------------
__global__ void fc_kernel(const float* __restrict__ in, const float* __restrict__ w,
                          const float* __restrict__ g, const float* __restrict__ bb,
                          float* __restrict__ out, int IN, int O){
  int i = blockIdx.x*blockDim.x + threadIdx.x;
  if (i >= BATCH*O) return;
  int b = i / O, o = i - b*O;
  const float* inb = in + (size_t)b*IN;
  const float* wo  = w + (size_t)o*IN;
  float s = 0.f;
  for (int c=0;c<IN;++c) s += inb[c]*wo[c];
  if (g){ s = s*bn_scale(g[o]) + bb[o]; s = fmaxf(s, 0.f); }
  out[i] = s;
}

extern "C" void kernel_launch(void* const* d_in, const int* in_sizes, int n_in,
                              void* d_out, int out_size, void* d_ws, size_t ws_size,
                              hipStream_t stream){
  const float* x   = (const float*)d_in[0];
  const float* w1  = (const float*)d_in[1];
  const float* w2  = (const float*)d_in[2];
  const float* w3  = (const float*)d_in[3];
  const float* w4  = (const float*)d_in[4];
  const float* w5  = (const float*)d_in[5];
  const float* fw1 = (const float*)d_in[6];
  const float* fw2 = (const float*)d_in[7];
  const float* fw3 = (const float*)d_in[8];
  const float* g1 = (const float*)d_in[9];  const float* b1 = (const float*)d_in[10];
  const float* g2 = (const float*)d_in[11]; const float* b2 = (const float*)d_in[12];
  const float* g3 = (const float*)d_in[13]; const float* b3 = (const float*)d_in[14];
  const float* g4 = (const float*)d_in[15]; const float* b4 = (const float*)d_in[16];
  const float* g5 = (const float*)d_in[17]; const float* b5 = (const float*)d_in[18];
  const float* g6 = (const float*)d_in[19]; const float* b6 = (const float*)d_in[20];
  const float* g7 = (const float*)d_in[21]; const float* b7 = (const float*)d_in[22];

  float* ws = (float*)d_ws;
  size_t off = 0;
  float* x1 = ws + off;  off += (size_t)BATCH*64*NPTS;
  float* x2 = ws + off;  off += (size_t)BATCH*64*NPTS;
  float* x3 = ws + off;  off += (size_t)BATCH*128*NPTS;
  float* x4 = ws + off;  off += (size_t)BATCH*256*NPTS;
  float* sq = ws + off;  off += (size_t)BATCH*NPTS;
  int*  idx = (int*)(ws + off); off += (size_t)BATCH*NPTS*KNN;
  float* out5 = ws + off; off += BATCH*1024;
  float* h6 = ws + off;   off += BATCH*512;
  float* h7 = ws + off;   off += BATCH*256;
  float* wnT1 = ws + off; off += 3*64;
  float* wdT1 = ws + off; off += 3*64;
  float* wnT2 = ws + off; off += 64*64;
  float* wdT2 = ws + off; off += 64*64;
  float* wnT3 = ws + off; off += 64*128;
  float* wdT3 = ws + off; off += 64*128;
  float* wnT4 = ws + off; off += 128*256;
  float* wdT4 = ws + off; off += 128*256;
  float* w5T  = ws + off; off += 512*1024;

  dim3 gridNN(NPTS, BATCH);

  // layer 1 (C=3 -> 64)
  sqnorm_kernel<<<64, 256, 0, stream>>>(x, sq, 3);
  knn_kernel<3><<<gridNN, 256, 0, stream>>>(x, sq, idx);
  wprep_kernel<<<1, 256, 0, stream>>>(w1, wnT1, wdT1, 64, 3);
  edgeconv_kernel<3,64><<<gridNN, 64, 0, stream>>>(x, idx, wnT1, wdT1, g1, b1, x1);
  // layer 2 (C=64 -> 64)
  sqnorm_kernel<<<64, 256, 0, stream>>>(x1, sq, 64);
  knn_kernel<64><<<gridNN, 256, 0, stream>>>(x1, sq, idx);
  wprep_kernel<<<16, 256, 0, stream>>>(w2, wnT2, wdT2, 64, 64);
  edgeconv_kernel<64,64><<<gridNN, 64, 0, stream>>>(x1, idx, wnT2, wdT2, g2, b2, x2);
  // layer 3 (C=64 -> 128)
  sqnorm_kernel<<<64, 256, 0, stream>>>(x2, sq, 64);
  knn_kernel<64><<<gridNN, 256, 0, stream>>>(x2, sq, idx);
  wprep_kernel<<<32, 256, 0, stream>>>(w3, wnT3, wdT3, 128, 64);
  edgeconv_kernel<64,128><<<gridNN, 128, 0, stream>>>(x2, idx, wnT3, wdT3, g3, b3, x3);
  // layer 4 (C=128 -> 256)
  sqnorm_kernel<<<64, 256, 0, stream>>>(x3, sq, 128);
  knn_kernel<128><<<gridNN, 256, 0, stream>>>(x3, sq, idx);
  wprep_kernel<<<128, 256, 0, stream>>>(w4, wnT4, wdT4, 256, 128);
  edgeconv_kernel<128,256><<<gridNN, 256, 0, stream>>>(x3, idx, wnT4, wdT4, g4, b4, x4);
  // conv5 + global max over n
  transpose_kernel<<<2048, 256, 0, stream>>>(w5, w5T, 1024, 512);
  zero_kernel<<<32, 256, 0, stream>>>(out5, BATCH*1024);
  conv5_kernel<<<dim3(32,16,8), 256, 0, stream>>>(x1, x2, x3, x4, w5T, g5, b5, out5);
  // FC head
  fc_kernel<<<16, 256, 0, stream>>>(out5, fw1, g6, b6, h6, 1024, 512);
  fc_kernel<<<8, 256, 0, stream>>>(h6, fw2, g7, b7, h7, 512, 256);
  fc_kernel<<<2, 256, 0, stream>>>(h7, fw3, nullptr, nullptr, (float*)d_out, 256, 40);
}

// Round 2
// 2151.315 us; speedup vs baseline: 1.3358x; 1.3358x over previous
//
#include <hip/hip_runtime.h>
#include <hip/hip_bf16.h>
#include <math.h>

#define BATCH 8
#define NPTS  2048
#define KNN   20
#define NEG_INF (-3.402823466e38f)

static __device__ __forceinline__ float bn_scale(float g){ return g * rsqrtf(1.0f + 1e-5f); }

// ---------------- squared norms per point ----------------
__global__ void sqnorm_kernel(const float* __restrict__ X, float* __restrict__ sq, int C){
  int i = blockIdx.x*blockDim.x + threadIdx.x;
  if (i >= BATCH*NPTS) return;
  int b = i / NPTS, n = i - b*NPTS;
  const float* xb = X + (size_t)b*C*NPTS + n;
  float s = 0.f;
  for (int c=0;c<C;++c){ float v = xb[(size_t)c*NPTS]; s += v*v; }
  sq[i] = s;
}

// ---------------- kNN v2: block = 8 points, register-tiled dist + wave-local top-20 ----
// Phase 1: each thread computes an 8(points)x8(candidates) register tile of dot products
//          (64 FMA per 8 global floats => 8x L2 reuse vs one-point-per-block).
// Phase 2: dist slab staged 4 rows at a time in LDS (32KB); each wave selects top-20 for
//          ONE point with zero barriers: per-lane incremental (max,idx) over 32 register
//          values, 6-step shfl argmax with smallest-index tie-break (matches lax.top_k).
template<int C>
__global__ __launch_bounds__(256, 4) void knn_kernel(const float* __restrict__ X,
                                                     const float* __restrict__ sq,
                                                     int* __restrict__ idxout){
  const int b = blockIdx.y;
  const int n0 = blockIdx.x * 8;
  const int t = threadIdx.x;
  __shared__ __align__(16) float dist[4][NPTS];
  __shared__ float ctrs[C][8];
  __shared__ float sqn[8];
  const float* xb = X + (size_t)b*C*NPTS;
  for (int i=t; i<C*8; i+=256){
    int c = i >> 3, p = i & 7;
    ctrs[c][p] = xb[(size_t)c*NPTS + n0 + p];
  }
  if (t < 8) sqn[t] = sq[b*NPTS + n0 + t];
  __syncthreads();

  // ---- phase 1: 8x8 register tile of distances, same accumulation order as v1 ----
  const int m0 = t * 8;
  float acc[8][8];
  #pragma unroll
  for (int i=0;i<8;++i)
    #pragma unroll
    for (int j=0;j<8;++j) acc[i][j] = 0.f;
  for (int c=0;c<C;++c){
    const float4 xa = *(const float4*)&xb[(size_t)c*NPTS + m0];
    const float4 xc = *(const float4*)&xb[(size_t)c*NPTS + m0 + 4];
    const float xm[8] = {xa.x,xa.y,xa.z,xa.w,xc.x,xc.y,xc.z,xc.w};
    #pragma unroll
    for (int i=0;i<8;++i){
      const float cv = ctrs[c][i];
      #pragma unroll
      for (int j=0;j<8;++j) acc[i][j] += cv*xm[j];
    }
  }
  {
    const float4 sa = *(const float4*)&sq[b*NPTS + m0];
    const float4 sb = *(const float4*)&sq[b*NPTS + m0 + 4];
    const float sm[8] = {sa.x,sa.y,sa.z,sa.w,sb.x,sb.y,sb.z,sb.w};
    #pragma unroll
    for (int i=0;i<8;++i){
      const float si = sqn[i];
      #pragma unroll
      for (int j=0;j<8;++j) acc[i][j] = 2.f*acc[i][j] - si - sm[j];
    }
  }

  const int wv = t >> 6, lane = t & 63;
  // ---- two selection rounds: rows 0..3 then rows 4..7 share the 32KB LDS slab ----
  #pragma unroll
  for (int rep=0; rep<2; ++rep){
    #pragma unroll
    for (int i=0;i<4;++i){
      *(float4*)&dist[i][m0]   = make_float4(acc[rep*4+i][0],acc[rep*4+i][1],acc[rep*4+i][2],acc[rep*4+i][3]);
      *(float4*)&dist[i][m0+4] = make_float4(acc[rep*4+i][4],acc[rep*4+i][5],acc[rep*4+i][6],acc[rep*4+i][7]);
    }
    __syncthreads();
    // wave wv selects for point (rep*4 + wv); lane holds m = lane + 64*j, j<32
    float v[32];
    float lmax = NEG_INF; int lidx = 0x7fffffff;
    #pragma unroll
    for (int j=0;j<32;++j){
      v[j] = dist[wv][lane + 64*j];
      if (v[j] > lmax){ lmax = v[j]; lidx = lane + 64*j; }   // first max => smallest m
    }
    int* row = idxout + ((size_t)b*NPTS + n0 + rep*4 + wv)*KNN;
    for (int sel=0; sel<KNN; ++sel){
      float bv = lmax; int bi = lidx;
      #pragma unroll
      for (int off=32; off>0; off>>=1){
        float ov = __shfl_down(bv, off, 64);
        int   oi = __shfl_down(bi, off, 64);
        if (ov > bv || (ov == bv && oi < bi)){ bv = ov; bi = oi; }
      }
      const int widx = __shfl(bi, 0, 64);
      if (lane == 0) row[sel] = widx;
      if ((widx & 63) == lane){
        const int jj = widx >> 6;
        #pragma unroll
        for (int j=0;j<32;++j) if (j == jj) v[j] = NEG_INF;
        lmax = NEG_INF; lidx = 0x7fffffff;
        #pragma unroll
        for (int j=0;j<32;++j) if (v[j] > lmax){ lmax = v[j]; lidx = lane + 64*j; }
      }
    }
    __syncthreads();   // all waves done reading slab before it is overwritten
  }
}

// ---------------- weight prep: wnT[c][o] = w[o][c]; wdT[c][o] = w[o][C+c]-w[o][c] ----------------
__global__ void wprep_kernel(const float* __restrict__ w, float* __restrict__ wnT,
                             float* __restrict__ wdT, int O, int C){
  int i = blockIdx.x*blockDim.x + threadIdx.x;
  if (i >= O*C) return;
  int c = i / O, o = i - c*O;
  float a = w[(size_t)o*2*C + c];
  wnT[(size_t)c*O + o] = a;
  wdT[(size_t)c*O + o] = w[(size_t)o*2*C + C + c] - a;
}

__global__ void transpose_kernel(const float* __restrict__ w, float* __restrict__ wT, int O, int C){
  int i = blockIdx.x*blockDim.x + threadIdx.x;
  if (i >= O*C) return;
  int c = i / O, o = i - c*O;
  wT[(size_t)c*O + o] = w[(size_t)o*C + c];
}

// ---------------- edge conv: block per (b,n), thread = output channel o ----------------
template<int C, int O>
__global__ __launch_bounds__(O) void edgeconv_kernel(const float* __restrict__ X,
    const int* __restrict__ idx, const float* __restrict__ wnT, const float* __restrict__ wdT,
    const float* __restrict__ g, const float* __restrict__ bb, float* __restrict__ out){
  const int n = blockIdx.x, b = blockIdx.y, t = threadIdx.x;
  __shared__ __align__(16) float ctr[(C+3)&~3];
  __shared__ __align__(16) float nbr[KNN][C];
  const float* xb = X + (size_t)b*C*NPTS;
  const int* row = idx + ((size_t)b*NPTS + n)*KNN;
  for (int c=t; c<C; c+=O) ctr[c] = xb[(size_t)c*NPTS + n];
  for (int i=t; i<KNN*C; i+=O){
    int k = i / C, c = i - k*C;
    nbr[k][c] = xb[(size_t)c*NPTS + row[k]];
  }
  __syncthreads();
  float acc[KNN];
  #pragma unroll
  for (int k=0;k<KNN;++k) acc[k] = 0.f;
  float cst = 0.f;
  if constexpr ((C & 3) == 0){
    for (int c=0;c<C;c+=4){
      const float w0 = wnT[(c+0)*O+t], w1 = wnT[(c+1)*O+t], w2 = wnT[(c+2)*O+t], w3 = wnT[(c+3)*O+t];
      const float4 ct = *(const float4*)&ctr[c];
      cst += ct.x*wdT[(c+0)*O+t] + ct.y*wdT[(c+1)*O+t] + ct.z*wdT[(c+2)*O+t] + ct.w*wdT[(c+3)*O+t];
      #pragma unroll
      for (int k=0;k<KNN;++k){
        const float4 nb = *(const float4*)&nbr[k][c];
        acc[k] += nb.x*w0 + nb.y*w1 + nb.z*w2 + nb.w*w3;
      }
    }
  } else {
    for (int c=0;c<C;++c){
      const float wn = wnT[c*O+t];
      cst += ctr[c]*wdT[c*O+t];
      #pragma unroll
      for (int k=0;k<KNN;++k) acc[k] += nbr[k][c]*wn;
    }
  }
  float best = NEG_INF;
  #pragma unroll
  for (int k=0;k<KNN;++k) best = fmaxf(best, acc[k]);
  float v = (best + cst) * bn_scale(g[t]) + bb[t];
  out[((size_t)b*O + t)*NPTS + n] = fmaxf(v, 0.f);
}

// ---------------- conv5 GEMM (512 -> 1024 per point) + bn/relu + max over n ----------------
__global__ __launch_bounds__(256) void conv5_kernel(const float* __restrict__ x1,
  const float* __restrict__ x2, const float* __restrict__ x3, const float* __restrict__ x4,
  const float* __restrict__ w5T, const float* __restrict__ g, const float* __restrict__ bb,
  float* __restrict__ out5){
  const int b = blockIdx.z;
  const int otile = blockIdx.y*64, ntile = blockIdx.x*64;
  const int t = threadIdx.x, tx = t & 15, ty = t >> 4;
  __shared__ __align__(16) float Xs[16][68];
  __shared__ __align__(16) float Ws[16][64];
  __shared__ float red[64][17];
  float acc[4][4] = {{0.f}};
  for (int c0=0;c0<512;c0+=16){
    const float* src; int coff;
    if (c0 < 64)      { src = x1 + (size_t)b*64*NPTS;  coff = c0; }
    else if (c0 <128) { src = x2 + (size_t)b*64*NPTS;  coff = c0-64; }
    else if (c0 <256) { src = x3 + (size_t)b*128*NPTS; coff = c0-128; }
    else              { src = x4 + (size_t)b*256*NPTS; coff = c0-256; }
    *(float4*)&Xs[ty][tx*4] = *(const float4*)&src[(size_t)(coff+ty)*NPTS + ntile + tx*4];
    *(float4*)&Ws[ty][tx*4] = *(const float4*)&w5T[(size_t)(c0+ty)*1024 + otile + tx*4];
    __syncthreads();
    #pragma unroll
    for (int i=0;i<16;++i){
      const float4 wv = *(const float4*)&Ws[i][ty*4];
      const float4 xv = *(const float4*)&Xs[i][tx*4];
      const float wa[4] = {wv.x,wv.y,wv.z,wv.w};
      const float xa[4] = {xv.x,xv.y,xv.z,xv.w};
      #pragma unroll
      for (int io=0;io<4;++io)
        #pragma unroll
        for (int in_=0;in_<4;++in_) acc[io][in_] += wa[io]*xa[in_];
    }
    __syncthreads();
  }
  #pragma unroll
  for (int io=0;io<4;++io){
    const int o = otile + ty*4 + io;
    const float gg = bn_scale(g[o]), bv = bb[o];
    float mx = NEG_INF;
    #pragma unroll
    for (int in_=0;in_<4;++in_) mx = fmaxf(mx, fmaxf(acc[io][in_]*gg + bv, 0.f));
    red[ty*4+io][tx] = mx;
  }
  __syncthreads();
  if (t < 64){
    float mx = red[t][0];
    #pragma unroll
    for (int j=1;j<16;++j) mx = fmaxf(mx, red[t][j]);
    atomicMax((int*)&out5[(size_t)b*1024 + otile + t], __float_as_int(mx));
  }
}

__global__ void zero_kernel(float* __restrict__ p, int nfloats){
  int i = blockIdx.x*blockDim.x + threadIdx.x;
  if (i < nfloats) p[i] = 0.f;
}

// ---------------- FC layers ----------------
__global__ void fc_kernel(const float* __restrict__ in, const float* __restrict__ w,
                          const float* __restrict__ g, const float* __restrict__ bb,
                          float* __restrict__ out, int IN, int O){
  int i = blockIdx.x*blockDim.x + threadIdx.x;
  if (i >= BATCH*O) return;
  int b = i / O, o = i - b*O;
  const float* inb = in + (size_t)b*IN;
  const float* wo  = w + (size_t)o*IN;
  float s = 0.f;
  for (int c=0;c<IN;++c) s += inb[c]*wo[c];
  if (g){ s = s*bn_scale(g[o]) + bb[o]; s = fmaxf(s, 0.f); }
  out[i] = s;
}

extern "C" void kernel_launch(void* const* d_in, const int* in_sizes, int n_in,
                              void* d_out, int out_size, void* d_ws, size_t ws_size,
                              hipStream_t stream){
  const float* x   = (const float*)d_in[0];
  const float* w1  = (const float*)d_in[1];
  const float* w2  = (const float*)d_in[2];
  const float* w3  = (const float*)d_in[3];
  const float* w4  = (const float*)d_in[4];
  const float* w5  = (const float*)d_in[5];
  const float* fw1 = (const float*)d_in[6];
  const float* fw2 = (const float*)d_in[7];
  const float* fw3 = (const float*)d_in[8];
  const float* g1 = (const float*)d_in[9];  const float* b1 = (const float*)d_in[10];
  const float* g2 = (const float*)d_in[11]; const float* b2 = (const float*)d_in[12];
  const float* g3 = (const float*)d_in[13]; const float* b3 = (const float*)d_in[14];
  const float* g4 = (const float*)d_in[15]; const float* b4 = (const float*)d_in[16];
  const float* g5 = (const float*)d_in[17]; const float* b5 = (const float*)d_in[18];
  const float* g6 = (const float*)d_in[19]; const float* b6 = (const float*)d_in[20];
  const float* g7 = (const float*)d_in[21]; const float* b7 = (const float*)d_in[22];

  float* ws = (float*)d_ws;
  size_t off = 0;
  float* x1 = ws + off;  off += (size_t)BATCH*64*NPTS;
  float* x2 = ws + off;  off += (size_t)BATCH*64*NPTS;
  float* x3 = ws + off;  off += (size_t)BATCH*128*NPTS;
  float* x4 = ws + off;  off += (size_t)BATCH*256*NPTS;
  float* sq = ws + off;  off += (size_t)BATCH*NPTS;
  int*  idx = (int*)(ws + off); off += (size_t)BATCH*NPTS*KNN;
  float* out5 = ws + off; off += BATCH*1024;
  float* h6 = ws + off;   off += BATCH*512;
  float* h7 = ws + off;   off += BATCH*256;
  float* wnT1 = ws + off; off += 3*64;
  float* wdT1 = ws + off; off += 3*64;
  float* wnT2 = ws + off; off += 64*64;
  float* wdT2 = ws + off; off += 64*64;
  float* wnT3 = ws + off; off += 64*128;
  float* wdT3 = ws + off; off += 64*128;
  float* wnT4 = ws + off; off += 128*256;
  float* wdT4 = ws + off; off += 128*256;
  float* w5T  = ws + off; off += 512*1024;

  dim3 gridNN(NPTS, BATCH);
  dim3 gridKNN(NPTS/8, BATCH);

  // layer 1 (C=3 -> 64)
  sqnorm_kernel<<<64, 256, 0, stream>>>(x, sq, 3);
  knn_kernel<3><<<gridKNN, 256, 0, stream>>>(x, sq, idx);
  wprep_kernel<<<1, 256, 0, stream>>>(w1, wnT1, wdT1, 64, 3);
  edgeconv_kernel<3,64><<<gridNN, 64, 0, stream>>>(x, idx, wnT1, wdT1, g1, b1, x1);
  // layer 2 (C=64 -> 64)
  sqnorm_kernel<<<64, 256, 0, stream>>>(x1, sq, 64);
  knn_kernel<64><<<gridKNN, 256, 0, stream>>>(x1, sq, idx);
  wprep_kernel<<<16, 256, 0, stream>>>(w2, wnT2, wdT2, 64, 64);
  edgeconv_kernel<64,64><<<gridNN, 64, 0, stream>>>(x1, idx, wnT2, wdT2, g2, b2, x2);
  // layer 3 (C=64 -> 128)
  sqnorm_kernel<<<64, 256, 0, stream>>>(x2, sq, 64);
  knn_kernel<64><<<gridKNN, 256, 0, stream>>>(x2, sq, idx);
  wprep_kernel<<<32, 256, 0, stream>>>(w3, wnT3, wdT3, 128, 64);
  edgeconv_kernel<64,128><<<gridNN, 128, 0, stream>>>(x2, idx, wnT3, wdT3, g3, b3, x3);
  // layer 4 (C=128 -> 256)
  sqnorm_kernel<<<64, 256, 0, stream>>>(x3, sq, 128);
  knn_kernel<128><<<gridKNN, 256, 0, stream>>>(x3, sq, idx);
  wprep_kernel<<<128, 256, 0, stream>>>(w4, wnT4, wdT4, 256, 128);
  edgeconv_kernel<128,256><<<gridNN, 256, 0, stream>>>(x3, idx, wnT4, wdT4, g4, b4, x4);
  // conv5 + global max over n
  transpose_kernel<<<2048, 256, 0, stream>>>(w5, w5T, 1024, 512);
  zero_kernel<<<32, 256, 0, stream>>>(out5, BATCH*1024);
  conv5_kernel<<<dim3(32,16,8), 256, 0, stream>>>(x1, x2, x3, x4, w5T, g5, b5, out5);
  // FC head
  fc_kernel<<<16, 256, 0, stream>>>(out5, fw1, g6, b6, h6, 1024, 512);
  fc_kernel<<<8, 256, 0, stream>>>(h6, fw2, g7, b7, h7, 512, 256);
  fc_kernel<<<2, 256, 0, stream>>>(h7, fw3, nullptr, nullptr, (float*)d_out, 256, 40);
}

// Round 3
// 1961.090 us; speedup vs baseline: 1.4654x; 1.0970x over previous
//
#include <hip/hip_runtime.h>
#include <hip/hip_bf16.h>
#include <math.h>

#define BATCH 8
#define NPTS  2048
#define KNN   20
#define NEG_INF (-3.402823466e38f)

static __device__ __forceinline__ float bn_scale(float g){ return g * rsqrtf(1.0f + 1e-5f); }

// ---------------- squared norms per point (reads channel-major [C][N]) ----------------
__global__ void sqnorm_kernel(const float* __restrict__ X, float* __restrict__ sq, int C){
  int i = blockIdx.x*blockDim.x + threadIdx.x;
  if (i >= BATCH*NPTS) return;
  int b = i / NPTS, n = i - b*NPTS;
  const float* xb = X + (size_t)b*C*NPTS + n;
  float s = 0.f;
  for (int c=0;c<C;++c){ float v = xb[(size_t)c*NPTS]; s += v*v; }
  sq[i] = s;
}

// ---------------- kNN v2 (unchanged from round 2; bit-exact top-20) ----------------
template<int C>
__global__ __launch_bounds__(256, 4) void knn_kernel(const float* __restrict__ X,
                                                     const float* __restrict__ sq,
                                                     int* __restrict__ idxout){
  const int b = blockIdx.y;
  const int n0 = blockIdx.x * 8;
  const int t = threadIdx.x;
  __shared__ __align__(16) float dist[4][NPTS];
  __shared__ float ctrs[C][8];
  __shared__ float sqn[8];
  const float* xb = X + (size_t)b*C*NPTS;
  for (int i=t; i<C*8; i+=256){
    int c = i >> 3, p = i & 7;
    ctrs[c][p] = xb[(size_t)c*NPTS + n0 + p];
  }
  if (t < 8) sqn[t] = sq[b*NPTS + n0 + t];
  __syncthreads();

  const int m0 = t * 8;
  float acc[8][8];
  #pragma unroll
  for (int i=0;i<8;++i)
    #pragma unroll
    for (int j=0;j<8;++j) acc[i][j] = 0.f;
  for (int c=0;c<C;++c){
    const float4 xa = *(const float4*)&xb[(size_t)c*NPTS + m0];
    const float4 xc = *(const float4*)&xb[(size_t)c*NPTS + m0 + 4];
    const float xm[8] = {xa.x,xa.y,xa.z,xa.w,xc.x,xc.y,xc.z,xc.w};
    #pragma unroll
    for (int i=0;i<8;++i){
      const float cv = ctrs[c][i];
      #pragma unroll
      for (int j=0;j<8;++j) acc[i][j] += cv*xm[j];
    }
  }
  {
    const float4 sa = *(const float4*)&sq[b*NPTS + m0];
    const float4 sb = *(const float4*)&sq[b*NPTS + m0 + 4];
    const float sm[8] = {sa.x,sa.y,sa.z,sa.w,sb.x,sb.y,sb.z,sb.w};
    #pragma unroll
    for (int i=0;i<8;++i){
      const float si = sqn[i];
      #pragma unroll
      for (int j=0;j<8;++j) acc[i][j] = 2.f*acc[i][j] - si - sm[j];
    }
  }

  const int wv = t >> 6, lane = t & 63;
  #pragma unroll
  for (int rep=0; rep<2; ++rep){
    #pragma unroll
    for (int i=0;i<4;++i){
      *(float4*)&dist[i][m0]   = make_float4(acc[rep*4+i][0],acc[rep*4+i][1],acc[rep*4+i][2],acc[rep*4+i][3]);
      *(float4*)&dist[i][m0+4] = make_float4(acc[rep*4+i][4],acc[rep*4+i][5],acc[rep*4+i][6],acc[rep*4+i][7]);
    }
    __syncthreads();
    float v[32];
    float lmax = NEG_INF; int lidx = 0x7fffffff;
    #pragma unroll
    for (int j=0;j<32;++j){
      v[j] = dist[wv][lane + 64*j];
      if (v[j] > lmax){ lmax = v[j]; lidx = lane + 64*j; }
    }
    int* row = idxout + ((size_t)b*NPTS + n0 + rep*4 + wv)*KNN;
    for (int sel=0; sel<KNN; ++sel){
      float bv = lmax; int bi = lidx;
      #pragma unroll
      for (int off=32; off>0; off>>=1){
        float ov = __shfl_down(bv, off, 64);
        int   oi = __shfl_down(bi, off, 64);
        if (ov > bv || (ov == bv && oi < bi)){ bv = ov; bi = oi; }
      }
      const int widx = __shfl(bi, 0, 64);
      if (lane == 0) row[sel] = widx;
      if ((widx & 63) == lane){
        const int jj = widx >> 6;
        #pragma unroll
        for (int j=0;j<32;++j) if (j == jj) v[j] = NEG_INF;
        lmax = NEG_INF; lidx = 0x7fffffff;
        #pragma unroll
        for (int j=0;j<32;++j) if (v[j] > lmax){ lmax = v[j]; lidx = lane + 64*j; }
      }
    }
    __syncthreads();
  }
}

// ---------------- weight prep: wnT[c][o] = w[o][c]; wdT[c][o] = w[o][C+c]-w[o][c] ----------------
__global__ void wprep_kernel(const float* __restrict__ w, float* __restrict__ wnT,
                             float* __restrict__ wdT, int O, int C){
  int i = blockIdx.x*blockDim.x + threadIdx.x;
  if (i >= O*C) return;
  int c = i / O, o = i - c*O;
  float a = w[(size_t)o*2*C + c];
  wnT[(size_t)c*O + o] = a;
  wdT[(size_t)c*O + o] = w[(size_t)o*2*C + C + c] - a;
}

// ---------------- generic tiled transpose: in[R][Cc] -> out[Cc][R], per z-slice ----------------
__global__ __launch_bounds__(256) void transpose2d_kernel(const float* __restrict__ in,
    float* __restrict__ out, int R, int Cc){
  __shared__ float tile[32][33];
  const size_t boff = (size_t)blockIdx.z * (size_t)R * Cc;
  const int c0 = blockIdx.x*32, r0 = blockIdx.y*32;
  const int tx = threadIdx.x & 31, ty = threadIdx.x >> 5;
  #pragma unroll
  for (int j=0;j<4;++j){
    int r = ty*4 + j;
    tile[r][tx] = in[boff + (size_t)(r0+r)*Cc + c0 + tx];
  }
  __syncthreads();
  #pragma unroll
  for (int j=0;j<4;++j){
    int r = ty*4 + j;
    out[boff + (size_t)(c0+r)*R + r0 + tx] = tile[tx][r];
  }
}

// ---------------- x -> xT0 [N][3] ----------------
__global__ void xt0_kernel(const float* __restrict__ x, float* __restrict__ xT0){
  int i = blockIdx.x*blockDim.x + threadIdx.x;
  if (i >= BATCH*NPTS) return;
  int b = i / NPTS, n = i - b*NPTS;
  const float* xb = x + (size_t)b*3*NPTS;
  float v0 = xb[n], v1 = xb[NPTS + n], v2 = xb[2*NPTS + n];
  float* o = xT0 + ((size_t)b*NPTS + n)*3;
  o[0]=v0; o[1]=v1; o[2]=v2;
}

// ---------------- edge conv layer 1 (C=3): 4 points per block, coalesced via xT0 ----------------
__global__ __launch_bounds__(256) void edgeconv1_kernel(const float* __restrict__ xT0,
    const int* __restrict__ idx, const float* __restrict__ wnT, const float* __restrict__ wdT,
    const float* __restrict__ g, const float* __restrict__ bb, float* __restrict__ outT){
  const int b = blockIdx.y, n0 = blockIdx.x*4, t = threadIdx.x;
  __shared__ float nbr[4][KNN][3];
  __shared__ float ctr[4][3];
  __shared__ int   idxs[4][KNN];
  const float* xb = xT0 + (size_t)b*NPTS*3;
  if (t < 4*KNN) idxs[t/KNN][t%KNN] = idx[((size_t)b*NPTS + n0 + t/KNN)*KNN + (t%KNN)];
  if (t >= 128 && t < 140){ int i = t-128; ctr[i/3][i%3] = xb[(size_t)(n0 + i/3)*3 + i%3]; }
  __syncthreads();
  for (int i=t; i<4*KNN*3; i+=256){
    int p = i/(KNN*3), r = i - p*(KNN*3), k = r/3, c = r - k*3;
    nbr[p][k][c] = xb[(size_t)idxs[p][k]*3 + c];
  }
  __syncthreads();
  const int p = t >> 6, o = t & 63;
  const float wn0 = wnT[o], wn1 = wnT[64+o], wn2 = wnT[128+o];
  const float cst = ctr[p][0]*wdT[o] + ctr[p][1]*wdT[64+o] + ctr[p][2]*wdT[128+o];
  float best = NEG_INF;
  #pragma unroll
  for (int k=0;k<KNN;++k){
    float a = nbr[p][k][0]*wn0 + nbr[p][k][1]*wn1 + nbr[p][k][2]*wn2;
    best = fmaxf(best, a);
  }
  float vv = (best + cst) * bn_scale(g[o]) + bb[o];
  outT[((size_t)b*NPTS + n0 + p)*64 + o] = fmaxf(vv, 0.f);
}

// ---------------- edge conv v3: block = 4 points (1 wave each), split-k halves ----------------
// Lane: half = lane>>5 handles k in [half*10, half*10+10); owns OJ=O/32 outputs o=j*32+(lane&31).
// Each nbr float4 LDS read feeds 4*OJ FMAs. Weights staged per CP-channel phase in LDS.
template<int C, int O>
__global__ __launch_bounds__(256) void edgeconv_v3(const float* __restrict__ xT,
    const int* __restrict__ idx, const float* __restrict__ wnT, const float* __restrict__ wdT,
    const float* __restrict__ g, const float* __restrict__ bb, float* __restrict__ outT){
  constexpr int OJ = O/32;
  constexpr int CP = (C == 128) ? 8 : 16;   // keep static LDS under 64KB
  constexpr int V  = KNN*C/4;
  const int b = blockIdx.y, n0 = blockIdx.x*4, t = threadIdx.x;
  __shared__ __align__(16) float nbrs[4][KNN][C];
  __shared__ __align__(16) float ctrs[4][C];
  __shared__ int   idxs[4][KNN];
  __shared__ float wn_s[CP][O];
  __shared__ float wd_s[CP][O];
  const float* xTb = xT + (size_t)b*NPTS*C;
  if (t < 4*KNN) idxs[t/KNN][t%KNN] = idx[((size_t)b*NPTS + n0 + t/KNN)*KNN + (t%KNN)];
  for (int i=t; i<4*C; i+=256) ctrs[i/C][i%C] = xTb[(size_t)(n0 + i/C)*C + (i%C)];
  __syncthreads();
  for (int i=t; i<4*V; i+=256){
    int p = i / V, r = i - p*V;
    int k = r / (C/4), c4 = r - k*(C/4);
    *(float4*)&nbrs[p][k][c4*4] = *(const float4*)&xTb[(size_t)idxs[p][k]*C + c4*4];
  }
  const int wv = t >> 6, l = t & 63, half = l >> 5, lo = l & 31;
  const int kbase = half * (KNN/2);
  float acc[KNN/2][OJ];
  float cst[OJ];
  #pragma unroll
  for (int k=0;k<KNN/2;++k)
    #pragma unroll
    for (int j=0;j<OJ;++j) acc[k][j] = 0.f;
  #pragma unroll
  for (int j=0;j<OJ;++j) cst[j] = 0.f;

  for (int ph=0; ph<C/CP; ++ph){
    __syncthreads();  // gather done (ph==0) / previous phase's reads done
    for (int i=t; i<CP*O; i+=256){
      int ci = i/O, o = i - ci*O;
      wn_s[ci][o] = wnT[(size_t)(ph*CP+ci)*O + o];
      wd_s[ci][o] = wdT[(size_t)(ph*CP+ci)*O + o];
    }
    __syncthreads();
    for (int ci=0; ci<CP; ci+=4){
      const int c = ph*CP + ci;
      float w[4][OJ], wd[4][OJ];
      #pragma unroll
      for (int i=0;i<4;++i)
        #pragma unroll
        for (int j=0;j<OJ;++j){ w[i][j] = wn_s[ci+i][j*32+lo]; wd[i][j] = wd_s[ci+i][j*32+lo]; }
      const float4 ct = *(const float4*)&ctrs[wv][c];
      const float cv[4] = {ct.x, ct.y, ct.z, ct.w};
      #pragma unroll
      for (int i=0;i<4;++i)
        #pragma unroll
        for (int j=0;j<OJ;++j) cst[j] += cv[i]*wd[i][j];
      #pragma unroll
      for (int k=0;k<KNN/2;++k){
        const float4 nb = *(const float4*)&nbrs[wv][kbase+k][c];
        const float na[4] = {nb.x, nb.y, nb.z, nb.w};
        #pragma unroll
        for (int i=0;i<4;++i)
          #pragma unroll
          for (int j=0;j<OJ;++j) acc[k][j] += na[i]*w[i][j];
      }
    }
  }

  const int n = n0 + wv;
  #pragma unroll
  for (int j=0;j<OJ;++j){
    float m = acc[0][j];
    #pragma unroll
    for (int k=1;k<KNN/2;++k) m = fmaxf(m, acc[k][j]);
    m = fmaxf(m, __shfl_xor(m, 32, 64));
    if (half == 0){
      const int o = j*32 + lo;
      float vv = (m + cst[j]) * bn_scale(g[o]) + bb[o];
      outT[((size_t)b*NPTS + n)*O + o] = fmaxf(vv, 0.f);
    }
  }
}

// ---------------- conv5 GEMM (512 -> 1024 per point) + bn/relu + max over n ----------------
__global__ __launch_bounds__(256) void conv5_kernel(const float* __restrict__ x1,
  const float* __restrict__ x2, const float* __restrict__ x3, const float* __restrict__ x4,
  const float* __restrict__ w5T, const float* __restrict__ g, const float* __restrict__ bb,
  float* __restrict__ out5){
  const int b = blockIdx.z;
  const int otile = blockIdx.y*64, ntile = blockIdx.x*64;
  const int t = threadIdx.x, tx = t & 15, ty = t >> 4;
  __shared__ __align__(16) float Xs[16][68];
  __shared__ __align__(16) float Ws[16][64];
  __shared__ float red[64][17];
  float acc[4][4] = {{0.f}};
  for (int c0=0;c0<512;c0+=16){
    const float* src; int coff;
    if (c0 < 64)      { src = x1 + (size_t)b*64*NPTS;  coff = c0; }
    else if (c0 <128) { src = x2 + (size_t)b*64*NPTS;  coff = c0-64; }
    else if (c0 <256) { src = x3 + (size_t)b*128*NPTS; coff = c0-128; }
    else              { src = x4 + (size_t)b*256*NPTS; coff = c0-256; }
    *(float4*)&Xs[ty][tx*4] = *(const float4*)&src[(size_t)(coff+ty)*NPTS + ntile + tx*4];
    *(float4*)&Ws[ty][tx*4] = *(const float4*)&w5T[(size_t)(c0+ty)*1024 + otile + tx*4];
    __syncthreads();
    #pragma unroll
    for (int i=0;i<16;++i){
      const float4 wv = *(const float4*)&Ws[i][ty*4];
      const float4 xv = *(const float4*)&Xs[i][tx*4];
      const float wa[4] = {wv.x,wv.y,wv.z,wv.w};
      const float xa[4] = {xv.x,xv.y,xv.z,xv.w};
      #pragma unroll
      for (int io=0;io<4;++io)
        #pragma unroll
        for (int in_=0;in_<4;++in_) acc[io][in_] += wa[io]*xa[in_];
    }
    __syncthreads();
  }
  #pragma unroll
  for (int io=0;io<4;++io){
    const int o = otile + ty*4 + io;
    const float gg = bn_scale(g[o]), bv = bb[o];
    float mx = NEG_INF;
    #pragma unroll
    for (int in_=0;in_<4;++in_) mx = fmaxf(mx, fmaxf(acc[io][in_]*gg + bv, 0.f));
    red[ty*4+io][tx] = mx;
  }
  __syncthreads();
  if (t < 64){
    float mx = red[t][0];
    #pragma unroll
    for (int j=1;j<16;++j) mx = fmaxf(mx, red[t][j]);
    atomicMax((int*)&out5[(size_t)b*1024 + otile + t], __float_as_int(mx));
  }
}

__global__ void zero_kernel(float* __restrict__ p, int nfloats){
  int i = blockIdx.x*blockDim.x + threadIdx.x;
  if (i < nfloats) p[i] = 0.f;
}

// ---------------- FC layers ----------------
__global__ void fc_kernel(const float* __restrict__ in, const float* __restrict__ w,
                          const float* __restrict__ g, const float* __restrict__ bb,
                          float* __restrict__ out, int IN, int O){
  int i = blockIdx.x*blockDim.x + threadIdx.x;
  if (i >= BATCH*O) return;
  int b = i / O, o = i - b*O;
  const float* inb = in + (size_t)b*IN;
  const float* wo  = w + (size_t)o*IN;
  float s = 0.f;
  for (int c=0;c<IN;++c) s += inb[c]*wo[c];
  if (g){ s = s*bn_scale(g[o]) + bb[o]; s = fmaxf(s, 0.f); }
  out[i] = s;
}

extern "C" void kernel_launch(void* const* d_in, const int* in_sizes, int n_in,
                              void* d_out, int out_size, void* d_ws, size_t ws_size,
                              hipStream_t stream){
  const float* x   = (const float*)d_in[0];
  const float* w1  = (const float*)d_in[1];
  const float* w2  = (const float*)d_in[2];
  const float* w3  = (const float*)d_in[3];
  const float* w4  = (const float*)d_in[4];
  const float* w5  = (const float*)d_in[5];
  const float* fw1 = (const float*)d_in[6];
  const float* fw2 = (const float*)d_in[7];
  const float* fw3 = (const float*)d_in[8];
  const float* g1 = (const float*)d_in[9];  const float* b1 = (const float*)d_in[10];
  const float* g2 = (const float*)d_in[11]; const float* b2 = (const float*)d_in[12];
  const float* g3 = (const float*)d_in[13]; const float* b3 = (const float*)d_in[14];
  const float* g4 = (const float*)d_in[15]; const float* b4 = (const float*)d_in[16];
  const float* g5 = (const float*)d_in[17]; const float* b5 = (const float*)d_in[18];
  const float* g6 = (const float*)d_in[19]; const float* b6 = (const float*)d_in[20];
  const float* g7 = (const float*)d_in[21]; const float* b7 = (const float*)d_in[22];

  float* ws = (float*)d_ws;
  size_t off = 0;
  float* x1  = ws + off; off += (size_t)BATCH*64*NPTS;
  float* x2  = ws + off; off += (size_t)BATCH*64*NPTS;
  float* x3  = ws + off; off += (size_t)BATCH*128*NPTS;
  float* x4  = ws + off; off += (size_t)BATCH*256*NPTS;
  float* x1T = ws + off; off += (size_t)BATCH*64*NPTS;
  float* x2T = ws + off; off += (size_t)BATCH*64*NPTS;
  float* x3T = ws + off; off += (size_t)BATCH*128*NPTS;
  float* x4T = ws + off; off += (size_t)BATCH*256*NPTS;
  float* xT0 = ws + off; off += (size_t)BATCH*3*NPTS;
  float* sq  = ws + off; off += (size_t)BATCH*NPTS;
  int*  idx  = (int*)(ws + off); off += (size_t)BATCH*NPTS*KNN;
  float* out5 = ws + off; off += BATCH*1024;
  float* h6 = ws + off;   off += BATCH*512;
  float* h7 = ws + off;   off += BATCH*256;
  float* wnT1 = ws + off; off += 3*64;
  float* wdT1 = ws + off; off += 3*64;
  float* wnT2 = ws + off; off += 64*64;
  float* wdT2 = ws + off; off += 64*64;
  float* wnT3 = ws + off; off += 64*128;
  float* wdT3 = ws + off; off += 64*128;
  float* wnT4 = ws + off; off += 128*256;
  float* wdT4 = ws + off; off += 128*256;
  float* w5T  = ws + off; off += 512*1024;

  dim3 gridKNN(NPTS/8, BATCH);
  dim3 gridEC(NPTS/4, BATCH);

  // layer 1 (C=3 -> 64)
  xt0_kernel<<<64, 256, 0, stream>>>(x, xT0);
  sqnorm_kernel<<<64, 256, 0, stream>>>(x, sq, 3);
  knn_kernel<3><<<gridKNN, 256, 0, stream>>>(x, sq, idx);
  wprep_kernel<<<1, 256, 0, stream>>>(w1, wnT1, wdT1, 64, 3);
  edgeconv1_kernel<<<gridEC, 256, 0, stream>>>(xT0, idx, wnT1, wdT1, g1, b1, x1T);
  transpose2d_kernel<<<dim3(2,64,BATCH), 256, 0, stream>>>(x1T, x1, NPTS, 64);
  // layer 2 (C=64 -> 64)
  sqnorm_kernel<<<64, 256, 0, stream>>>(x1, sq, 64);
  knn_kernel<64><<<gridKNN, 256, 0, stream>>>(x1, sq, idx);
  wprep_kernel<<<16, 256, 0, stream>>>(w2, wnT2, wdT2, 64, 64);
  edgeconv_v3<64,64><<<gridEC, 256, 0, stream>>>(x1T, idx, wnT2, wdT2, g2, b2, x2T);
  transpose2d_kernel<<<dim3(2,64,BATCH), 256, 0, stream>>>(x2T, x2, NPTS, 64);
  // layer 3 (C=64 -> 128)
  sqnorm_kernel<<<64, 256, 0, stream>>>(x2, sq, 64);
  knn_kernel<64><<<gridKNN, 256, 0, stream>>>(x2, sq, idx);
  wprep_kernel<<<32, 256, 0, stream>>>(w3, wnT3, wdT3, 128, 64);
  edgeconv_v3<64,128><<<gridEC, 256, 0, stream>>>(x2T, idx, wnT3, wdT3, g3, b3, x3T);
  transpose2d_kernel<<<dim3(4,64,BATCH), 256, 0, stream>>>(x3T, x3, NPTS, 128);
  // layer 4 (C=128 -> 256)
  sqnorm_kernel<<<64, 256, 0, stream>>>(x3, sq, 128);
  knn_kernel<128><<<gridKNN, 256, 0, stream>>>(x3, sq, idx);
  wprep_kernel<<<128, 256, 0, stream>>>(w4, wnT4, wdT4, 256, 128);
  edgeconv_v3<128,256><<<gridEC, 256, 0, stream>>>(x3T, idx, wnT4, wdT4, g4, b4, x4T);
  transpose2d_kernel<<<dim3(8,64,BATCH), 256, 0, stream>>>(x4T, x4, NPTS, 256);
  // conv5 + global max over n
  transpose2d_kernel<<<dim3(16,32,1), 256, 0, stream>>>(w5, w5T, 1024, 512);
  zero_kernel<<<32, 256, 0, stream>>>(out5, BATCH*1024);
  conv5_kernel<<<dim3(32,16,8), 256, 0, stream>>>(x1, x2, x3, x4, w5T, g5, b5, out5);
  // FC head
  fc_kernel<<<16, 256, 0, stream>>>(out5, fw1, g6, b6, h6, 1024, 512);
  fc_kernel<<<8, 256, 0, stream>>>(h6, fw2, g7, b7, h7, 512, 256);
  fc_kernel<<<2, 256, 0, stream>>>(h7, fw3, nullptr, nullptr, (float*)d_out, 256, 40);
}

// Round 4
// 1460.430 us; speedup vs baseline: 1.9677x; 1.3428x over previous
//
#include <hip/hip_runtime.h>
#include <hip/hip_bf16.h>
#include <math.h>

#define BATCH 8
#define NPTS  2048
#define KNN   20
#define NEG_INF (-3.402823466e38f)

static __device__ __forceinline__ float bn_scale(float g){ return g * rsqrtf(1.0f + 1e-5f); }

// bf16 round-to-nearest-even
static __device__ __forceinline__ unsigned short bf16r(float f){
  unsigned int u = __float_as_uint(f);
  unsigned int r = (u + 0x7fffu + ((u >> 16) & 1u)) >> 16;
  return (unsigned short)r;
}
// ordered-int encode/decode for float max via atomicMax(uint)
static __device__ __forceinline__ unsigned int fenc(float f){
  unsigned int u = __float_as_uint(f);
  return (u & 0x80000000u) ? ~u : (u | 0x80000000u);
}
static __device__ __forceinline__ float fdec(unsigned int e){
  return __uint_as_float((e & 0x80000000u) ? (e & 0x7fffffffu) : ~e);
}

using bfrag = __attribute__((ext_vector_type(8))) short;  // 8 bf16 (4 VGPRs)
using f32x4 = __attribute__((ext_vector_type(4))) float;  // 4 fp32 acc

// ---------------- squared norms per point (reads channel-major [C][N]) ----------------
__global__ void sqnorm_kernel(const float* __restrict__ X, float* __restrict__ sq, int C){
  int i = blockIdx.x*blockDim.x + threadIdx.x;
  if (i >= BATCH*NPTS) return;
  int b = i / NPTS, n = i - b*NPTS;
  const float* xb = X + (size_t)b*C*NPTS + n;
  float s = 0.f;
  for (int c=0;c<C;++c){ float v = xb[(size_t)c*NPTS]; s += v*v; }
  sq[i] = s;
}

// ---------------- kNN v2 (bit-exact top-20, matches lax.top_k ties) ----------------
template<int C>
__global__ __launch_bounds__(256, 4) void knn_kernel(const float* __restrict__ X,
                                                     const float* __restrict__ sq,
                                                     int* __restrict__ idxout){
  const int b = blockIdx.y;
  const int n0 = blockIdx.x * 8;
  const int t = threadIdx.x;
  __shared__ __align__(16) float dist[4][NPTS];
  __shared__ float ctrs[C][8];
  __shared__ float sqn[8];
  const float* xb = X + (size_t)b*C*NPTS;
  for (int i=t; i<C*8; i+=256){
    int c = i >> 3, p = i & 7;
    ctrs[c][p] = xb[(size_t)c*NPTS + n0 + p];
  }
  if (t < 8) sqn[t] = sq[b*NPTS + n0 + t];
  __syncthreads();

  const int m0 = t * 8;
  float acc[8][8];
  #pragma unroll
  for (int i=0;i<8;++i)
    #pragma unroll
    for (int j=0;j<8;++j) acc[i][j] = 0.f;
  for (int c=0;c<C;++c){
    const float4 xa = *(const float4*)&xb[(size_t)c*NPTS + m0];
    const float4 xc = *(const float4*)&xb[(size_t)c*NPTS + m0 + 4];
    const float xm[8] = {xa.x,xa.y,xa.z,xa.w,xc.x,xc.y,xc.z,xc.w};
    #pragma unroll
    for (int i=0;i<8;++i){
      const float cv = ctrs[c][i];
      #pragma unroll
      for (int j=0;j<8;++j) acc[i][j] += cv*xm[j];
    }
  }
  {
    const float4 sa = *(const float4*)&sq[b*NPTS + m0];
    const float4 sb = *(const float4*)&sq[b*NPTS + m0 + 4];
    const float sm[8] = {sa.x,sa.y,sa.z,sa.w,sb.x,sb.y,sb.z,sb.w};
    #pragma unroll
    for (int i=0;i<8;++i){
      const float si = sqn[i];
      #pragma unroll
      for (int j=0;j<8;++j) acc[i][j] = 2.f*acc[i][j] - si - sm[j];
    }
  }

  const int wv = t >> 6, lane = t & 63;
  #pragma unroll
  for (int rep=0; rep<2; ++rep){
    #pragma unroll
    for (int i=0;i<4;++i){
      *(float4*)&dist[i][m0]   = make_float4(acc[rep*4+i][0],acc[rep*4+i][1],acc[rep*4+i][2],acc[rep*4+i][3]);
      *(float4*)&dist[i][m0+4] = make_float4(acc[rep*4+i][4],acc[rep*4+i][5],acc[rep*4+i][6],acc[rep*4+i][7]);
    }
    __syncthreads();
    float v[32];
    float lmax = NEG_INF; int lidx = 0x7fffffff;
    #pragma unroll
    for (int j=0;j<32;++j){
      v[j] = dist[wv][lane + 64*j];
      if (v[j] > lmax){ lmax = v[j]; lidx = lane + 64*j; }
    }
    int* row = idxout + ((size_t)b*NPTS + n0 + rep*4 + wv)*KNN;
    for (int sel=0; sel<KNN; ++sel){
      float bv = lmax; int bi = lidx;
      #pragma unroll
      for (int off=32; off>0; off>>=1){
        float ov = __shfl_down(bv, off, 64);
        int   oi = __shfl_down(bi, off, 64);
        if (ov > bv || (ov == bv && oi < bi)){ bv = ov; bi = oi; }
      }
      const int widx = __shfl(bi, 0, 64);
      if (lane == 0) row[sel] = widx;
      if ((widx & 63) == lane){
        const int jj = widx >> 6;
        #pragma unroll
        for (int j=0;j<32;++j) if (j == jj) v[j] = NEG_INF;
        lmax = NEG_INF; lidx = 0x7fffffff;
        #pragma unroll
        for (int j=0;j<32;++j) if (v[j] > lmax){ lmax = v[j]; lidx = lane + 64*j; }
      }
    }
    __syncthreads();
  }
}

// ---------------- fp32 weight prep (layer 1 only): wnT[c][o], wdT[c][o] ----------------
__global__ void wprep_kernel(const float* __restrict__ w, float* __restrict__ wnT,
                             float* __restrict__ wdT, int O, int C){
  int i = blockIdx.x*blockDim.x + threadIdx.x;
  if (i >= O*C) return;
  int c = i / O, o = i - c*O;
  float a = w[(size_t)o*2*C + c];
  wnT[(size_t)c*O + o] = a;
  wdT[(size_t)c*O + o] = w[(size_t)o*2*C + C + c] - a;
}

// ---------------- bf16 weight prep (layers 2-4): wn[o][c], wd[o][c] (k contiguous) -----
__global__ void wprep_bf_kernel(const float* __restrict__ w, unsigned short* __restrict__ wn,
                                unsigned short* __restrict__ wd, int O, int C){
  int i = blockIdx.x*blockDim.x + threadIdx.x;
  if (i >= O*C) return;
  int o = i / C, c = i - o*C;
  float a = w[(size_t)o*2*C + c];
  float d = w[(size_t)o*2*C + C + c] - a;
  wn[(size_t)o*C + c] = bf16r(a);
  wd[(size_t)o*C + c] = bf16r(d);
}

// ---------------- generic tiled transpose: in[R][Cc] -> out[Cc][R], per z-slice ----------------
__global__ __launch_bounds__(256) void transpose2d_kernel(const float* __restrict__ in,
    float* __restrict__ out, int R, int Cc){
  __shared__ float tile[32][33];
  const size_t boff = (size_t)blockIdx.z * (size_t)R * Cc;
  const int c0 = blockIdx.x*32, r0 = blockIdx.y*32;
  const int tx = threadIdx.x & 31, ty = threadIdx.x >> 5;
  #pragma unroll
  for (int j=0;j<4;++j){
    int r = ty*4 + j;
    tile[r][tx] = in[boff + (size_t)(r0+r)*Cc + c0 + tx];
  }
  __syncthreads();
  #pragma unroll
  for (int j=0;j<4;++j){
    int r = ty*4 + j;
    out[boff + (size_t)(c0+r)*R + r0 + tx] = tile[tx][r];
  }
}

// ---------------- x -> xT0 [N][3] ----------------
__global__ void xt0_kernel(const float* __restrict__ x, float* __restrict__ xT0){
  int i = blockIdx.x*blockDim.x + threadIdx.x;
  if (i >= BATCH*NPTS) return;
  int b = i / NPTS, n = i - b*NPTS;
  const float* xb = x + (size_t)b*3*NPTS;
  float v0 = xb[n], v1 = xb[NPTS + n], v2 = xb[2*NPTS + n];
  float* o = xT0 + ((size_t)b*NPTS + n)*3;
  o[0]=v0; o[1]=v1; o[2]=v2;
}

// ---------------- edge conv layer 1 (C=3, fp32): 4 points per block ----------------
__global__ __launch_bounds__(256) void edgeconv1_kernel(const float* __restrict__ xT0,
    const int* __restrict__ idx, const float* __restrict__ wnT, const float* __restrict__ wdT,
    const float* __restrict__ g, const float* __restrict__ bb, float* __restrict__ outT){
  const int b = blockIdx.y, n0 = blockIdx.x*4, t = threadIdx.x;
  __shared__ float nbr[4][KNN][3];
  __shared__ float ctr[4][3];
  __shared__ int   idxs[4][KNN];
  const float* xb = xT0 + (size_t)b*NPTS*3;
  if (t < 4*KNN) idxs[t/KNN][t%KNN] = idx[((size_t)b*NPTS + n0 + t/KNN)*KNN + (t%KNN)];
  if (t >= 128 && t < 140){ int i = t-128; ctr[i/3][i%3] = xb[(size_t)(n0 + i/3)*3 + i%3]; }
  __syncthreads();
  for (int i=t; i<4*KNN*3; i+=256){
    int p = i/(KNN*3), r = i - p*(KNN*3), k = r/3, c = r - k*3;
    nbr[p][k][c] = xb[(size_t)idxs[p][k]*3 + c];
  }
  __syncthreads();
  const int p = t >> 6, o = t & 63;
  const float wn0 = wnT[o], wn1 = wnT[64+o], wn2 = wnT[128+o];
  const float cst = ctr[p][0]*wdT[o] + ctr[p][1]*wdT[64+o] + ctr[p][2]*wdT[128+o];
  float best = NEG_INF;
  #pragma unroll
  for (int k=0;k<KNN;++k){
    float a = nbr[p][k][0]*wn0 + nbr[p][k][1]*wn1 + nbr[p][k][2]*wn2;
    best = fmaxf(best, a);
  }
  float vv = (best + cst) * bn_scale(g[o]) + bb[o];
  outT[((size_t)b*NPTS + n0 + p)*64 + o] = fmaxf(vv, 0.f);
}

// ---------------- edge conv MFMA (bf16): block = 4 points ----------------
// A (LDS, bf16): rows 0..95 = 4 pts x 24 (20 nbrs + 4 dup-pad), 96..99 = centers, 100..111 = 0.
// B (global, bf16 [O][C]): wn for m-tiles 0..5, wd for m-tile 6 (center rows).
// D = A.B accumulated fp32; max over k via ordered-int atomicMax into LDS res[4][O].
template<int C, int O>
__global__ __launch_bounds__(256) void edgeconv_mfma(const float* __restrict__ xT,
    const int* __restrict__ idx,
    const unsigned short* __restrict__ wn_bf, const unsigned short* __restrict__ wd_bf,
    const float* __restrict__ g, const float* __restrict__ bb, float* __restrict__ outT){
  constexpr int ROWS = 112;        // 7 m-tiles of 16
  constexpr int CP   = C + 8;      // padded row (bf16): 16B-aligned stride, conflict-free b128
  constexpr int KS   = C / 32;     // k-steps per tile
  constexpr int NTW  = O / 64;     // n-tiles per wave (O/16 tiles over 4 waves)
  __shared__ __align__(16) unsigned short A[ROWS][CP];
  __shared__ unsigned int res[4][O];
  __shared__ float cst_s[4][O];
  __shared__ int idxs[4][KNN];
  const int b = blockIdx.y, n0 = blockIdx.x*4, t = threadIdx.x;
  const float* xTb = xT + (size_t)b*NPTS*C;
  if (t < 4*KNN) idxs[t/KNN][t%KNN] = idx[((size_t)b*NPTS + n0 + t/KNN)*KNN + (t%KNN)];
  for (int i=t; i<4*O; i+=256) res[i/O][i & (O-1)] = 0u;   // 0 < fenc(any finite)
  __syncthreads();
  // gather + fp32->bf16 convert into A
  for (int i=t; i<ROWS*(C/4); i+=256){
    int r = i/(C/4), c4 = i - r*(C/4);
    float4 v = make_float4(0.f,0.f,0.f,0.f);
    if (r < 96){
      int p = r/24, kk = r - p*24;
      int src = idxs[p][kk < KNN ? kk : 0];        // pad rows duplicate nbr 0 (max-neutral)
      v = *(const float4*)&xTb[(size_t)src*C + c4*4];
    } else if (r < 100){
      v = *(const float4*)&xTb[(size_t)(n0 + (r-96))*C + c4*4];
    }
    unsigned int lo = (unsigned int)bf16r(v.x) | ((unsigned int)bf16r(v.y) << 16);
    unsigned int hi = (unsigned int)bf16r(v.z) | ((unsigned int)bf16r(v.w) << 16);
    *(uint2*)&A[r][c4*4] = make_uint2(lo, hi);
  }
  __syncthreads();

  const int wv = t >> 6, l = t & 63;
  const int lane15 = l & 15, quad = l >> 4;
  // preload Bn fragments for this wave's n-tiles
  bfrag Bn[NTW][KS];
  #pragma unroll
  for (int nt=0; nt<NTW; ++nt){
    const int col = (wv*NTW + nt)*16 + lane15;
    #pragma unroll
    for (int s=0; s<KS; ++s)
      Bn[nt][s] = *(const bfrag*)&wn_bf[(size_t)col*C + s*32 + quad*8];
  }
  #pragma unroll
  for (int mt=0; mt<7; ++mt){
    bfrag Af[KS];
    #pragma unroll
    for (int s=0; s<KS; ++s)
      Af[s] = *(const bfrag*)&A[mt*16 + lane15][s*32 + quad*8];
    if (mt < 6){
      const int rbase = mt*16 + quad*4;
      const int p = rbase / 24;                 // 4-row group never straddles a 24-row point
      #pragma unroll
      for (int nt=0; nt<NTW; ++nt){
        f32x4 acc = {0.f,0.f,0.f,0.f};
        #pragma unroll
        for (int s=0; s<KS; ++s)
          acc = __builtin_amdgcn_mfma_f32_16x16x32_bf16(Af[s], Bn[nt][s], acc, 0, 0, 0);
        float m = fmaxf(fmaxf(acc[0], acc[1]), fmaxf(acc[2], acc[3]));
        const int col = (wv*NTW + nt)*16 + lane15;
        atomicMax(&res[p][col], fenc(m));
      }
    } else {
      // center rows 96..99 (quad 0) with wd weights
      #pragma unroll
      for (int nt=0; nt<NTW; ++nt){
        const int col = (wv*NTW + nt)*16 + lane15;
        f32x4 acc = {0.f,0.f,0.f,0.f};
        #pragma unroll
        for (int s=0; s<KS; ++s){
          bfrag Bd = *(const bfrag*)&wd_bf[(size_t)col*C + s*32 + quad*8];
          acc = __builtin_amdgcn_mfma_f32_16x16x32_bf16(Af[s], Bd, acc, 0, 0, 0);
        }
        if (quad == 0){
          #pragma unroll
          for (int r=0;r<4;++r) cst_s[r][col] = acc[r];
        }
      }
    }
  }
  __syncthreads();
  for (int i=t; i<4*O; i+=256){
    int p = i/O, o = i - p*O;
    float mx = fdec(res[p][o]);
    float vv = (mx + cst_s[p][o]) * bn_scale(g[o]) + bb[o];
    outT[((size_t)b*NPTS + n0 + p)*O + o] = fmaxf(vv, 0.f);
  }
}

// ---------------- conv5 GEMM (512 -> 1024 per point) + bn/relu + max over n ----------------
__global__ __launch_bounds__(256) void conv5_kernel(const float* __restrict__ x1,
  const float* __restrict__ x2, const float* __restrict__ x3, const float* __restrict__ x4,
  const float* __restrict__ w5T, const float* __restrict__ g, const float* __restrict__ bb,
  float* __restrict__ out5){
  const int b = blockIdx.z;
  const int otile = blockIdx.y*64, ntile = blockIdx.x*64;
  const int t = threadIdx.x, tx = t & 15, ty = t >> 4;
  __shared__ __align__(16) float Xs[16][68];
  __shared__ __align__(16) float Ws[16][64];
  __shared__ float red[64][17];
  float acc[4][4] = {{0.f}};
  for (int c0=0;c0<512;c0+=16){
    const float* src; int coff;
    if (c0 < 64)      { src = x1 + (size_t)b*64*NPTS;  coff = c0; }
    else if (c0 <128) { src = x2 + (size_t)b*64*NPTS;  coff = c0-64; }
    else if (c0 <256) { src = x3 + (size_t)b*128*NPTS; coff = c0-128; }
    else              { src = x4 + (size_t)b*256*NPTS; coff = c0-256; }
    *(float4*)&Xs[ty][tx*4] = *(const float4*)&src[(size_t)(coff+ty)*NPTS + ntile + tx*4];
    *(float4*)&Ws[ty][tx*4] = *(const float4*)&w5T[(size_t)(c0+ty)*1024 + otile + tx*4];
    __syncthreads();
    #pragma unroll
    for (int i=0;i<16;++i){
      const float4 wv = *(const float4*)&Ws[i][ty*4];
      const float4 xv = *(const float4*)&Xs[i][tx*4];
      const float wa[4] = {wv.x,wv.y,wv.z,wv.w};
      const float xa[4] = {xv.x,xv.y,xv.z,xv.w};
      #pragma unroll
      for (int io=0;io<4;++io)
        #pragma unroll
        for (int in_=0;in_<4;++in_) acc[io][in_] += wa[io]*xa[in_];
    }
    __syncthreads();
  }
  #pragma unroll
  for (int io=0;io<4;++io){
    const int o = otile + ty*4 + io;
    const float gg = bn_scale(g[o]), bv = bb[o];
    float mx = NEG_INF;
    #pragma unroll
    for (int in_=0;in_<4;++in_) mx = fmaxf(mx, fmaxf(acc[io][in_]*gg + bv, 0.f));
    red[ty*4+io][tx] = mx;
  }
  __syncthreads();
  if (t < 64){
    float mx = red[t][0];
    #pragma unroll
    for (int j=1;j<16;++j) mx = fmaxf(mx, red[t][j]);
    atomicMax((int*)&out5[(size_t)b*1024 + otile + t], __float_as_int(mx));
  }
}

__global__ void zero_kernel(float* __restrict__ p, int nfloats){
  int i = blockIdx.x*blockDim.x + threadIdx.x;
  if (i < nfloats) p[i] = 0.f;
}

// ---------------- FC layers ----------------
__global__ void fc_kernel(const float* __restrict__ in, const float* __restrict__ w,
                          const float* __restrict__ g, const float* __restrict__ bb,
                          float* __restrict__ out, int IN, int O){
  int i = blockIdx.x*blockDim.x + threadIdx.x;
  if (i >= BATCH*O) return;
  int b = i / O, o = i - b*O;
  const float* inb = in + (size_t)b*IN;
  const float* wo  = w + (size_t)o*IN;
  float s = 0.f;
  for (int c=0;c<IN;++c) s += inb[c]*wo[c];
  if (g){ s = s*bn_scale(g[o]) + bb[o]; s = fmaxf(s, 0.f); }
  out[i] = s;
}

extern "C" void kernel_launch(void* const* d_in, const int* in_sizes, int n_in,
                              void* d_out, int out_size, void* d_ws, size_t ws_size,
                              hipStream_t stream){
  const float* x   = (const float*)d_in[0];
  const float* w1  = (const float*)d_in[1];
  const float* w2  = (const float*)d_in[2];
  const float* w3  = (const float*)d_in[3];
  const float* w4  = (const float*)d_in[4];
  const float* w5  = (const float*)d_in[5];
  const float* fw1 = (const float*)d_in[6];
  const float* fw2 = (const float*)d_in[7];
  const float* fw3 = (const float*)d_in[8];
  const float* g1 = (const float*)d_in[9];  const float* b1 = (const float*)d_in[10];
  const float* g2 = (const float*)d_in[11]; const float* b2 = (const float*)d_in[12];
  const float* g3 = (const float*)d_in[13]; const float* b3 = (const float*)d_in[14];
  const float* g4 = (const float*)d_in[15]; const float* b4 = (const float*)d_in[16];
  const float* g5 = (const float*)d_in[17]; const float* b5 = (const float*)d_in[18];
  const float* g6 = (const float*)d_in[19]; const float* b6 = (const float*)d_in[20];
  const float* g7 = (const float*)d_in[21]; const float* b7 = (const float*)d_in[22];

  float* ws = (float*)d_ws;
  size_t off = 0;
  float* x1  = ws + off; off += (size_t)BATCH*64*NPTS;
  float* x2  = ws + off; off += (size_t)BATCH*64*NPTS;
  float* x3  = ws + off; off += (size_t)BATCH*128*NPTS;
  float* x4  = ws + off; off += (size_t)BATCH*256*NPTS;
  float* x1T = ws + off; off += (size_t)BATCH*64*NPTS;
  float* x2T = ws + off; off += (size_t)BATCH*64*NPTS;
  float* x3T = ws + off; off += (size_t)BATCH*128*NPTS;
  float* x4T = ws + off; off += (size_t)BATCH*256*NPTS;
  float* xT0 = ws + off; off += (size_t)BATCH*3*NPTS;
  float* sq  = ws + off; off += (size_t)BATCH*NPTS;
  int*  idx  = (int*)(ws + off); off += (size_t)BATCH*NPTS*KNN;
  float* out5 = ws + off; off += BATCH*1024;
  float* h6 = ws + off;   off += BATCH*512;
  float* h7 = ws + off;   off += BATCH*256;
  float* wnT1 = ws + off; off += 3*64;
  float* wdT1 = ws + off; off += 3*64;
  unsigned short* wn2 = (unsigned short*)(ws + off); off += 64*64/2;
  unsigned short* wd2 = (unsigned short*)(ws + off); off += 64*64/2;
  unsigned short* wn3 = (unsigned short*)(ws + off); off += 128*64/2;
  unsigned short* wd3 = (unsigned short*)(ws + off); off += 128*64/2;
  unsigned short* wn4 = (unsigned short*)(ws + off); off += 256*128/2;
  unsigned short* wd4 = (unsigned short*)(ws + off); off += 256*128/2;
  float* w5T  = ws + off; off += 512*1024;

  dim3 gridKNN(NPTS/8, BATCH);
  dim3 gridEC(NPTS/4, BATCH);

  // layer 1 (C=3 -> 64, fp32)
  xt0_kernel<<<64, 256, 0, stream>>>(x, xT0);
  sqnorm_kernel<<<64, 256, 0, stream>>>(x, sq, 3);
  knn_kernel<3><<<gridKNN, 256, 0, stream>>>(x, sq, idx);
  wprep_kernel<<<1, 256, 0, stream>>>(w1, wnT1, wdT1, 64, 3);
  edgeconv1_kernel<<<gridEC, 256, 0, stream>>>(xT0, idx, wnT1, wdT1, g1, b1, x1T);
  transpose2d_kernel<<<dim3(2,64,BATCH), 256, 0, stream>>>(x1T, x1, NPTS, 64);
  // layer 2 (C=64 -> 64, bf16 MFMA)
  sqnorm_kernel<<<64, 256, 0, stream>>>(x1, sq, 64);
  knn_kernel<64><<<gridKNN, 256, 0, stream>>>(x1, sq, idx);
  wprep_bf_kernel<<<16, 256, 0, stream>>>(w2, wn2, wd2, 64, 64);
  edgeconv_mfma<64,64><<<gridEC, 256, 0, stream>>>(x1T, idx, wn2, wd2, g2, b2, x2T);
  transpose2d_kernel<<<dim3(2,64,BATCH), 256, 0, stream>>>(x2T, x2, NPTS, 64);
  // layer 3 (C=64 -> 128, bf16 MFMA)
  sqnorm_kernel<<<64, 256, 0, stream>>>(x2, sq, 64);
  knn_kernel<64><<<gridKNN, 256, 0, stream>>>(x2, sq, idx);
  wprep_bf_kernel<<<32, 256, 0, stream>>>(w3, wn3, wd3, 128, 64);
  edgeconv_mfma<64,128><<<gridEC, 256, 0, stream>>>(x2T, idx, wn3, wd3, g3, b3, x3T);
  transpose2d_kernel<<<dim3(4,64,BATCH), 256, 0, stream>>>(x3T, x3, NPTS, 128);
  // layer 4 (C=128 -> 256, bf16 MFMA)
  sqnorm_kernel<<<64, 256, 0, stream>>>(x3, sq, 128);
  knn_kernel<128><<<gridKNN, 256, 0, stream>>>(x3, sq, idx);
  wprep_bf_kernel<<<128, 256, 0, stream>>>(w4, wn4, wd4, 256, 128);
  edgeconv_mfma<128,256><<<gridEC, 256, 0, stream>>>(x3T, idx, wn4, wd4, g4, b4, x4T);
  transpose2d_kernel<<<dim3(8,64,BATCH), 256, 0, stream>>>(x4T, x4, NPTS, 256);
  // conv5 + global max over n
  transpose2d_kernel<<<dim3(16,32,1), 256, 0, stream>>>(w5, w5T, 1024, 512);
  zero_kernel<<<32, 256, 0, stream>>>(out5, BATCH*1024);
  conv5_kernel<<<dim3(32,16,8), 256, 0, stream>>>(x1, x2, x3, x4, w5T, g5, b5, out5);
  // FC head
  fc_kernel<<<16, 256, 0, stream>>>(out5, fw1, g6, b6, h6, 1024, 512);
  fc_kernel<<<8, 256, 0, stream>>>(h6, fw2, g7, b7, h7, 512, 256);
  fc_kernel<<<2, 256, 0, stream>>>(h7, fw3, nullptr, nullptr, (float*)d_out, 256, 40);
}

// Round 5
// 1397.056 us; speedup vs baseline: 2.0570x; 1.0454x over previous
//
#include <hip/hip_runtime.h>
#include <hip/hip_bf16.h>
#include <math.h>

#define BATCH 8
#define NPTS  2048
#define KNN   20
#define NEG_INF (-3.402823466e38f)

static __device__ __forceinline__ float bn_scale(float g){ return g * rsqrtf(1.0f + 1e-5f); }

// bf16 round-to-nearest-even
static __device__ __forceinline__ unsigned short bf16r(float f){
  unsigned int u = __float_as_uint(f);
  unsigned int r = (u + 0x7fffu + ((u >> 16) & 1u)) >> 16;
  return (unsigned short)r;
}
// ordered-int encode/decode for float max via atomicMax(uint)
static __device__ __forceinline__ unsigned int fenc(float f){
  unsigned int u = __float_as_uint(f);
  return (u & 0x80000000u) ? ~u : (u | 0x80000000u);
}
static __device__ __forceinline__ float fdec(unsigned int e){
  return __uint_as_float((e & 0x80000000u) ? (e & 0x7fffffffu) : ~e);
}

using bfrag = __attribute__((ext_vector_type(8))) short;  // 8 bf16 (4 VGPRs)
using f32x4 = __attribute__((ext_vector_type(4))) float;  // 4 fp32 acc

// ---------------- squared norms per point (reads channel-major [C][N]) ----------------
__global__ void sqnorm_kernel(const float* __restrict__ X, float* __restrict__ sq, int C){
  int i = blockIdx.x*blockDim.x + threadIdx.x;
  if (i >= BATCH*NPTS) return;
  int b = i / NPTS, n = i - b*NPTS;
  const float* xb = X + (size_t)b*C*NPTS + n;
  float s = 0.f;
  for (int c=0;c<C;++c){ float v = xb[(size_t)c*NPTS]; s += v*v; }
  sq[i] = s;
}

// ---------------- kNN v3: no spills (launch_bounds(256,2)), LDS-based selection ----------
template<int C>
__global__ __launch_bounds__(256, 2) void knn_kernel(const float* __restrict__ X,
                                                     const float* __restrict__ sq,
                                                     int* __restrict__ idxout){
  const int b = blockIdx.y;
  const int n0 = blockIdx.x * 8;
  const int t = threadIdx.x;
  __shared__ __align__(16) float dist[4][NPTS];
  __shared__ float ctrs[C][8];
  __shared__ float sqn[8];
  const float* xb = X + (size_t)b*C*NPTS;
  for (int i=t; i<C*8; i+=256){
    int c = i >> 3, p = i & 7;
    ctrs[c][p] = xb[(size_t)c*NPTS + n0 + p];
  }
  if (t < 8) sqn[t] = sq[b*NPTS + n0 + t];
  __syncthreads();

  const int m0 = t * 8;
  float acc[8][8];
  #pragma unroll
  for (int i=0;i<8;++i)
    #pragma unroll
    for (int j=0;j<8;++j) acc[i][j] = 0.f;
  for (int c=0;c<C;++c){
    const float4 xa = *(const float4*)&xb[(size_t)c*NPTS + m0];
    const float4 xc = *(const float4*)&xb[(size_t)c*NPTS + m0 + 4];
    const float xm[8] = {xa.x,xa.y,xa.z,xa.w,xc.x,xc.y,xc.z,xc.w};
    #pragma unroll
    for (int i=0;i<8;++i){
      const float cv = ctrs[c][i];
      #pragma unroll
      for (int j=0;j<8;++j) acc[i][j] += cv*xm[j];
    }
  }
  {
    const float4 sa = *(const float4*)&sq[b*NPTS + m0];
    const float4 sb = *(const float4*)&sq[b*NPTS + m0 + 4];
    const float sm[8] = {sa.x,sa.y,sa.z,sa.w,sb.x,sb.y,sb.z,sb.w};
    #pragma unroll
    for (int i=0;i<8;++i){
      const float si = sqn[i];
      #pragma unroll
      for (int j=0;j<8;++j) acc[i][j] = 2.f*acc[i][j] - si - sm[j];
    }
  }

  const int wv = t >> 6, lane = t & 63;
  #pragma unroll
  for (int rep=0; rep<2; ++rep){
    #pragma unroll
    for (int i=0;i<4;++i){
      *(float4*)&dist[i][m0]   = make_float4(acc[rep*4+i][0],acc[rep*4+i][1],acc[rep*4+i][2],acc[rep*4+i][3]);
      *(float4*)&dist[i][m0+4] = make_float4(acc[rep*4+i][4],acc[rep*4+i][5],acc[rep*4+i][6],acc[rep*4+i][7]);
    }
    __syncthreads();
    // wave wv selects for point (rep*4 + wv); lane owns m = lane + 64*j, j<32, values in LDS
    float lmax = NEG_INF; int lidx = 0x7fffffff;
    #pragma unroll
    for (int j=0;j<32;++j){
      float vv = dist[wv][lane + 64*j];
      if (vv > lmax){ lmax = vv; lidx = lane + 64*j; }   // ascending m => first max kept
    }
    int* row = idxout + ((size_t)b*NPTS + n0 + rep*4 + wv)*KNN;
    for (int sel=0; sel<KNN; ++sel){
      float bv = lmax; int bi = lidx;
      #pragma unroll
      for (int off=32; off>0; off>>=1){
        float ov = __shfl_down(bv, off, 64);
        int   oi = __shfl_down(bi, off, 64);
        if (ov > bv || (ov == bv && oi < bi)){ bv = ov; bi = oi; }
      }
      const int widx = __shfl(bi, 0, 64);
      if (lane == 0) row[sel] = widx;
      if ((widx & 63) == lane){
        dist[wv][widx] = NEG_INF;          // invalidate in LDS (same lane rereads below)
        lmax = NEG_INF; lidx = 0x7fffffff;
        #pragma unroll
        for (int j=0;j<32;++j){
          float vv = dist[wv][lane + 64*j];
          if (vv > lmax){ lmax = vv; lidx = lane + 64*j; }
        }
      }
    }
    __syncthreads();
  }
}

// ---------------- fp32 weight prep (layer 1 only): wnT[c][o], wdT[c][o] ----------------
__global__ void wprep_kernel(const float* __restrict__ w, float* __restrict__ wnT,
                             float* __restrict__ wdT, int O, int C){
  int i = blockIdx.x*blockDim.x + threadIdx.x;
  if (i >= O*C) return;
  int c = i / O, o = i - c*O;
  float a = w[(size_t)o*2*C + c];
  wnT[(size_t)c*O + o] = a;
  wdT[(size_t)c*O + o] = w[(size_t)o*2*C + C + c] - a;
}

// ---------------- bf16 weight prep (layers 2-4): wn[o][c], wd[o][c] (k contiguous) -----
__global__ void wprep_bf_kernel(const float* __restrict__ w, unsigned short* __restrict__ wn,
                                unsigned short* __restrict__ wd, int O, int C){
  int i = blockIdx.x*blockDim.x + threadIdx.x;
  if (i >= O*C) return;
  int o = i / C, c = i - o*C;
  float a = w[(size_t)o*2*C + c];
  float d = w[(size_t)o*2*C + C + c] - a;
  wn[(size_t)o*C + c] = bf16r(a);
  wd[(size_t)o*C + c] = bf16r(d);
}

// ---------------- generic tiled transpose: in[R][Cc] -> out[Cc][R], per z-slice ----------------
__global__ __launch_bounds__(256) void transpose2d_kernel(const float* __restrict__ in,
    float* __restrict__ out, int R, int Cc){
  __shared__ float tile[32][33];
  const size_t boff = (size_t)blockIdx.z * (size_t)R * Cc;
  const int c0 = blockIdx.x*32, r0 = blockIdx.y*32;
  const int tx = threadIdx.x & 31, ty = threadIdx.x >> 5;
  #pragma unroll
  for (int j=0;j<4;++j){
    int r = ty*4 + j;
    tile[r][tx] = in[boff + (size_t)(r0+r)*Cc + c0 + tx];
  }
  __syncthreads();
  #pragma unroll
  for (int j=0;j<4;++j){
    int r = ty*4 + j;
    out[boff + (size_t)(c0+r)*R + r0 + tx] = tile[tx][r];
  }
}

// ---------------- x -> xT0 [N][3] ----------------
__global__ void xt0_kernel(const float* __restrict__ x, float* __restrict__ xT0){
  int i = blockIdx.x*blockDim.x + threadIdx.x;
  if (i >= BATCH*NPTS) return;
  int b = i / NPTS, n = i - b*NPTS;
  const float* xb = x + (size_t)b*3*NPTS;
  float v0 = xb[n], v1 = xb[NPTS + n], v2 = xb[2*NPTS + n];
  float* o = xT0 + ((size_t)b*NPTS + n)*3;
  o[0]=v0; o[1]=v1; o[2]=v2;
}

// ---------------- edge conv layer 1 (C=3, fp32): 4 points per block ----------------
__global__ __launch_bounds__(256) void edgeconv1_kernel(const float* __restrict__ xT0,
    const int* __restrict__ idx, const float* __restrict__ wnT, const float* __restrict__ wdT,
    const float* __restrict__ g, const float* __restrict__ bb, float* __restrict__ outT){
  const int b = blockIdx.y, n0 = blockIdx.x*4, t = threadIdx.x;
  __shared__ float nbr[4][KNN][3];
  __shared__ float ctr[4][3];
  __shared__ int   idxs[4][KNN];
  const float* xb = xT0 + (size_t)b*NPTS*3;
  if (t < 4*KNN) idxs[t/KNN][t%KNN] = idx[((size_t)b*NPTS + n0 + t/KNN)*KNN + (t%KNN)];
  if (t >= 128 && t < 140){ int i = t-128; ctr[i/3][i%3] = xb[(size_t)(n0 + i/3)*3 + i%3]; }
  __syncthreads();
  for (int i=t; i<4*KNN*3; i+=256){
    int p = i/(KNN*3), r = i - p*(KNN*3), k = r/3, c = r - k*3;
    nbr[p][k][c] = xb[(size_t)idxs[p][k]*3 + c];
  }
  __syncthreads();
  const int p = t >> 6, o = t & 63;
  const float wn0 = wnT[o], wn1 = wnT[64+o], wn2 = wnT[128+o];
  const float cst = ctr[p][0]*wdT[o] + ctr[p][1]*wdT[64+o] + ctr[p][2]*wdT[128+o];
  float best = NEG_INF;
  #pragma unroll
  for (int k=0;k<KNN;++k){
    float a = nbr[p][k][0]*wn0 + nbr[p][k][1]*wn1 + nbr[p][k][2]*wn2;
    best = fmaxf(best, a);
  }
  float vv = (best + cst) * bn_scale(g[o]) + bb[o];
  outT[((size_t)b*NPTS + n0 + p)*64 + o] = fmaxf(vv, 0.f);
}

// ---------------- edge conv MFMA (bf16): block = 4 points ----------------
template<int C, int O>
__global__ __launch_bounds__(256) void edgeconv_mfma(const float* __restrict__ xT,
    const int* __restrict__ idx,
    const unsigned short* __restrict__ wn_bf, const unsigned short* __restrict__ wd_bf,
    const float* __restrict__ g, const float* __restrict__ bb, float* __restrict__ outT){
  constexpr int ROWS = 112;        // 7 m-tiles of 16
  constexpr int CP   = C + 8;      // padded row (bf16): 16B-aligned stride, conflict-free b128
  constexpr int KS   = C / 32;     // k-steps per tile
  constexpr int NTW  = O / 64;     // n-tiles per wave (O/16 tiles over 4 waves)
  __shared__ __align__(16) unsigned short A[ROWS][CP];
  __shared__ unsigned int res[4][O];
  __shared__ float cst_s[4][O];
  __shared__ int idxs[4][KNN];
  const int b = blockIdx.y, n0 = blockIdx.x*4, t = threadIdx.x;
  const float* xTb = xT + (size_t)b*NPTS*C;
  if (t < 4*KNN) idxs[t/KNN][t%KNN] = idx[((size_t)b*NPTS + n0 + t/KNN)*KNN + (t%KNN)];
  for (int i=t; i<4*O; i+=256) res[i/O][i & (O-1)] = 0u;   // 0 < fenc(any finite)
  __syncthreads();
  // gather + fp32->bf16 convert into A
  for (int i=t; i<ROWS*(C/4); i+=256){
    int r = i/(C/4), c4 = i - r*(C/4);
    float4 v = make_float4(0.f,0.f,0.f,0.f);
    if (r < 96){
      int p = r/24, kk = r - p*24;
      int src = idxs[p][kk < KNN ? kk : 0];        // pad rows duplicate nbr 0 (max-neutral)
      v = *(const float4*)&xTb[(size_t)src*C + c4*4];
    } else if (r < 100){
      v = *(const float4*)&xTb[(size_t)(n0 + (r-96))*C + c4*4];
    }
    unsigned int lo = (unsigned int)bf16r(v.x) | ((unsigned int)bf16r(v.y) << 16);
    unsigned int hi = (unsigned int)bf16r(v.z) | ((unsigned int)bf16r(v.w) << 16);
    *(uint2*)&A[r][c4*4] = make_uint2(lo, hi);
  }
  __syncthreads();

  const int wv = t >> 6, l = t & 63;
  const int lane15 = l & 15, quad = l >> 4;
  // preload Bn fragments for this wave's n-tiles
  bfrag Bn[NTW][KS];
  #pragma unroll
  for (int nt=0; nt<NTW; ++nt){
    const int col = (wv*NTW + nt)*16 + lane15;
    #pragma unroll
    for (int s=0; s<KS; ++s)
      Bn[nt][s] = *(const bfrag*)&wn_bf[(size_t)col*C + s*32 + quad*8];
  }
  #pragma unroll
  for (int mt=0; mt<7; ++mt){
    bfrag Af[KS];
    #pragma unroll
    for (int s=0; s<KS; ++s)
      Af[s] = *(const bfrag*)&A[mt*16 + lane15][s*32 + quad*8];
    if (mt < 6){
      const int rbase = mt*16 + quad*4;
      const int p = rbase / 24;                 // 4-row group never straddles a 24-row point
      #pragma unroll
      for (int nt=0; nt<NTW; ++nt){
        f32x4 acc = {0.f,0.f,0.f,0.f};
        #pragma unroll
        for (int s=0; s<KS; ++s)
          acc = __builtin_amdgcn_mfma_f32_16x16x32_bf16(Af[s], Bn[nt][s], acc, 0, 0, 0);
        float m = fmaxf(fmaxf(acc[0], acc[1]), fmaxf(acc[2], acc[3]));
        const int col = (wv*NTW + nt)*16 + lane15;
        atomicMax(&res[p][col], fenc(m));
      }
    } else {
      // center rows 96..99 (quad 0) with wd weights
      #pragma unroll
      for (int nt=0; nt<NTW; ++nt){
        const int col = (wv*NTW + nt)*16 + lane15;
        f32x4 acc = {0.f,0.f,0.f,0.f};
        #pragma unroll
        for (int s=0; s<KS; ++s){
          bfrag Bd = *(const bfrag*)&wd_bf[(size_t)col*C + s*32 + quad*8];
          acc = __builtin_amdgcn_mfma_f32_16x16x32_bf16(Af[s], Bd, acc, 0, 0, 0);
        }
        if (quad == 0){
          #pragma unroll
          for (int r=0;r<4;++r) cst_s[r][col] = acc[r];
        }
      }
    }
  }
  __syncthreads();
  for (int i=t; i<4*O; i+=256){
    int p = i/O, o = i - p*O;
    float mx = fdec(res[p][o]);
    float vv = (mx + cst_s[p][o]) * bn_scale(g[o]) + bb[o];
    outT[((size_t)b*NPTS + n0 + p)*O + o] = fmaxf(vv, 0.f);
  }
}

// ---------------- conv5 GEMM (512 -> 1024 per point) + bn/relu + max over n ----------------
__global__ __launch_bounds__(256) void conv5_kernel(const float* __restrict__ x1,
  const float* __restrict__ x2, const float* __restrict__ x3, const float* __restrict__ x4,
  const float* __restrict__ w5T, const float* __restrict__ g, const float* __restrict__ bb,
  float* __restrict__ out5){
  const int b = blockIdx.z;
  const int otile = blockIdx.y*64, ntile = blockIdx.x*64;
  const int t = threadIdx.x, tx = t & 15, ty = t >> 4;
  __shared__ __align__(16) float Xs[16][68];
  __shared__ __align__(16) float Ws[16][64];
  __shared__ float red[64][17];
  float acc[4][4] = {{0.f}};
  for (int c0=0;c0<512;c0+=16){
    const float* src; int coff;
    if (c0 < 64)      { src = x1 + (size_t)b*64*NPTS;  coff = c0; }
    else if (c0 <128) { src = x2 + (size_t)b*64*NPTS;  coff = c0-64; }
    else if (c0 <256) { src = x3 + (size_t)b*128*NPTS; coff = c0-128; }
    else              { src = x4 + (size_t)b*256*NPTS; coff = c0-256; }
    *(float4*)&Xs[ty][tx*4] = *(const float4*)&src[(size_t)(coff+ty)*NPTS + ntile + tx*4];
    *(float4*)&Ws[ty][tx*4] = *(const float4*)&w5T[(size_t)(c0+ty)*1024 + otile + tx*4];
    __syncthreads();
    #pragma unroll
    for (int i=0;i<16;++i){
      const float4 wv = *(const float4*)&Ws[i][ty*4];
      const float4 xv = *(const float4*)&Xs[i][tx*4];
      const float wa[4] = {wv.x,wv.y,wv.z,wv.w};
      const float xa[4] = {xv.x,xv.y,xv.z,xv.w};
      #pragma unroll
      for (int io=0;io<4;++io)
        #pragma unroll
        for (int in_=0;in_<4;++in_) acc[io][in_] += wa[io]*xa[in_];
    }
    __syncthreads();
  }
  #pragma unroll
  for (int io=0;io<4;++io){
    const int o = otile + ty*4 + io;
    const float gg = bn_scale(g[o]), bv = bb[o];
    float mx = NEG_INF;
    #pragma unroll
    for (int in_=0;in_<4;++in_) mx = fmaxf(mx, fmaxf(acc[io][in_]*gg + bv, 0.f));
    red[ty*4+io][tx] = mx;
  }
  __syncthreads();
  if (t < 64){
    float mx = red[t][0];
    #pragma unroll
    for (int j=1;j<16;++j) mx = fmaxf(mx, red[t][j]);
    atomicMax((int*)&out5[(size_t)b*1024 + otile + t], __float_as_int(mx));
  }
}

__global__ void zero_kernel(float* __restrict__ p, int nfloats){
  int i = blockIdx.x*blockDim.x + threadIdx.x;
  if (i < nfloats) p[i] = 0.f;
}

// ---------------- FC layers ----------------
__global__ void fc_kernel(const float* __restrict__ in, const float* __restrict__ w,
                          const float* __restrict__ g, const float* __restrict__ bb,
                          float* __restrict__ out, int IN, int O){
  int i = blockIdx.x*blockDim.x + threadIdx.x;
  if (i >= BATCH*O) return;
  int b = i / O, o = i - b*O;
  const float* inb = in + (size_t)b*IN;
  const float* wo  = w + (size_t)o*IN;
  float s = 0.f;
  for (int c=0;c<IN;++c) s += inb[c]*wo[c];
  if (g){ s = s*bn_scale(g[o]) + bb[o]; s = fmaxf(s, 0.f); }
  out[i] = s;
}

extern "C" void kernel_launch(void* const* d_in, const int* in_sizes, int n_in,
                              void* d_out, int out_size, void* d_ws, size_t ws_size,
                              hipStream_t stream){
  const float* x   = (const float*)d_in[0];
  const float* w1  = (const float*)d_in[1];
  const float* w2  = (const float*)d_in[2];
  const float* w3  = (const float*)d_in[3];
  const float* w4  = (const float*)d_in[4];
  const float* w5  = (const float*)d_in[5];
  const float* fw1 = (const float*)d_in[6];
  const float* fw2 = (const float*)d_in[7];
  const float* fw3 = (const float*)d_in[8];
  const float* g1 = (const float*)d_in[9];  const float* b1 = (const float*)d_in[10];
  const float* g2 = (const float*)d_in[11]; const float* b2 = (const float*)d_in[12];
  const float* g3 = (const float*)d_in[13]; const float* b3 = (const float*)d_in[14];
  const float* g4 = (const float*)d_in[15]; const float* b4 = (const float*)d_in[16];
  const float* g5 = (const float*)d_in[17]; const float* b5 = (const float*)d_in[18];
  const float* g6 = (const float*)d_in[19]; const float* b6 = (const float*)d_in[20];
  const float* g7 = (const float*)d_in[21]; const float* b7 = (const float*)d_in[22];

  float* ws = (float*)d_ws;
  size_t off = 0;
  float* x1  = ws + off; off += (size_t)BATCH*64*NPTS;
  float* x2  = ws + off; off += (size_t)BATCH*64*NPTS;
  float* x3  = ws + off; off += (size_t)BATCH*128*NPTS;
  float* x4  = ws + off; off += (size_t)BATCH*256*NPTS;
  float* x1T = ws + off; off += (size_t)BATCH*64*NPTS;
  float* x2T = ws + off; off += (size_t)BATCH*64*NPTS;
  float* x3T = ws + off; off += (size_t)BATCH*128*NPTS;
  float* x4T = ws + off; off += (size_t)BATCH*256*NPTS;
  float* xT0 = ws + off; off += (size_t)BATCH*3*NPTS;
  float* sq  = ws + off; off += (size_t)BATCH*NPTS;
  int*  idx  = (int*)(ws + off); off += (size_t)BATCH*NPTS*KNN;
  float* out5 = ws + off; off += BATCH*1024;
  float* h6 = ws + off;   off += BATCH*512;
  float* h7 = ws + off;   off += BATCH*256;
  float* wnT1 = ws + off; off += 3*64;
  float* wdT1 = ws + off; off += 3*64;
  unsigned short* wn2 = (unsigned short*)(ws + off); off += 64*64/2;
  unsigned short* wd2 = (unsigned short*)(ws + off); off += 64*64/2;
  unsigned short* wn3 = (unsigned short*)(ws + off); off += 128*64/2;
  unsigned short* wd3 = (unsigned short*)(ws + off); off += 128*64/2;
  unsigned short* wn4 = (unsigned short*)(ws + off); off += 256*128/2;
  unsigned short* wd4 = (unsigned short*)(ws + off); off += 256*128/2;
  float* w5T  = ws + off; off += 512*1024;

  dim3 gridKNN(NPTS/8, BATCH);
  dim3 gridEC(NPTS/4, BATCH);

  // layer 1 (C=3 -> 64, fp32)
  xt0_kernel<<<64, 256, 0, stream>>>(x, xT0);
  sqnorm_kernel<<<64, 256, 0, stream>>>(x, sq, 3);
  knn_kernel<3><<<gridKNN, 256, 0, stream>>>(x, sq, idx);
  wprep_kernel<<<1, 256, 0, stream>>>(w1, wnT1, wdT1, 64, 3);
  edgeconv1_kernel<<<gridEC, 256, 0, stream>>>(xT0, idx, wnT1, wdT1, g1, b1, x1T);
  transpose2d_kernel<<<dim3(2,64,BATCH), 256, 0, stream>>>(x1T, x1, NPTS, 64);
  // layer 2 (C=64 -> 64, bf16 MFMA)
  sqnorm_kernel<<<64, 256, 0, stream>>>(x1, sq, 64);
  knn_kernel<64><<<gridKNN, 256, 0, stream>>>(x1, sq, idx);
  wprep_bf_kernel<<<16, 256, 0, stream>>>(w2, wn2, wd2, 64, 64);
  edgeconv_mfma<64,64><<<gridEC, 256, 0, stream>>>(x1T, idx, wn2, wd2, g2, b2, x2T);
  transpose2d_kernel<<<dim3(2,64,BATCH), 256, 0, stream>>>(x2T, x2, NPTS, 64);
  // layer 3 (C=64 -> 128, bf16 MFMA)
  sqnorm_kernel<<<64, 256, 0, stream>>>(x2, sq, 64);
  knn_kernel<64><<<gridKNN, 256, 0, stream>>>(x2, sq, idx);
  wprep_bf_kernel<<<32, 256, 0, stream>>>(w3, wn3, wd3, 128, 64);
  edgeconv_mfma<64,128><<<gridEC, 256, 0, stream>>>(x2T, idx, wn3, wd3, g3, b3, x3T);
  transpose2d_kernel<<<dim3(4,64,BATCH), 256, 0, stream>>>(x3T, x3, NPTS, 128);
  // layer 4 (C=128 -> 256, bf16 MFMA)
  sqnorm_kernel<<<64, 256, 0, stream>>>(x3, sq, 128);
  knn_kernel<128><<<gridKNN, 256, 0, stream>>>(x3, sq, idx);
  wprep_bf_kernel<<<128, 256, 0, stream>>>(w4, wn4, wd4, 256, 128);
  edgeconv_mfma<128,256><<<gridEC, 256, 0, stream>>>(x3T, idx, wn4, wd4, g4, b4, x4T);
  transpose2d_kernel<<<dim3(8,64,BATCH), 256, 0, stream>>>(x4T, x4, NPTS, 256);
  // conv5 + global max over n
  transpose2d_kernel<<<dim3(16,32,1), 256, 0, stream>>>(w5, w5T, 1024, 512);
  zero_kernel<<<32, 256, 0, stream>>>(out5, BATCH*1024);
  conv5_kernel<<<dim3(32,16,8), 256, 0, stream>>>(x1, x2, x3, x4, w5T, g5, b5, out5);
  // FC head
  fc_kernel<<<16, 256, 0, stream>>>(out5, fw1, g6, b6, h6, 1024, 512);
  fc_kernel<<<8, 256, 0, stream>>>(h6, fw2, g7, b7, h7, 512, 256);
  fc_kernel<<<2, 256, 0, stream>>>(h7, fw3, nullptr, nullptr, (float*)d_out, 256, 40);
}